// Round 1
// baseline (1558.484 us; speedup 1.0000x reference)
//
#include <hip/hip_runtime.h>
#include <math.h>

// Problem constants (from reference)
#define B_SZ 8192
#define D_DIM 512
#define C_DIM 1000
#define K_EXP 8
#define TEMP_INV 5.0f     // 1/0.2
#define EPS_N 1e-8f

// ---------------- fp32 tiled GEMM: C = act(A @ Bw + bias) ----------------
// A: [M, Kd] row-major (per-expert stride aBatch)
// Bw: [Kd, N] row-major (per-expert stride bBatch)
// blockIdx.z = expert. BM=128, BN=128, BK=16, 256 threads, per-thread 16x4.
#define BM 128
#define BN 128
#define BK 16
#define TM 16
#define TN 4

__global__ __launch_bounds__(256) void gemm_bias_act(
    const float* __restrict__ A, long long aBatch,
    const float* __restrict__ Bw, long long bBatch,
    const float* __restrict__ bias, int biasBatch,
    float* __restrict__ Cc, long long cBatch,
    int M, int N, int Kd, int relu)
{
    const int k = blockIdx.z;
    A    += (size_t)k * aBatch;
    Bw   += (size_t)k * bBatch;
    bias += (size_t)k * biasBatch;
    Cc   += (size_t)k * cBatch;

    const int m0 = blockIdx.y * BM;
    const int n0 = blockIdx.x * BN;
    const int tid = threadIdx.x;

    __shared__ float As[BK][BM + 4];   // +4 pad: transposed stores land 2-way (free)
    __shared__ float Bs[BK][BN];

    float acc[TM][TN];
#pragma unroll
    for (int i = 0; i < TM; i++)
#pragma unroll
        for (int j = 0; j < TN; j++) acc[i][j] = 0.f;

    const int tx = tid & 31;   // col group: cols n0 + tx*4 .. +3
    const int ty = tid >> 5;   // row group: rows m0 + ty*16 .. +15

    const int ar  = tid >> 2;  // A-load row (plus 64*i)
    const int ac4 = tid & 3;   // A-load float4 index along Kd
    const int bkr = tid >> 5;  // B-load row (plus 8*i)
    const int bc32 = tid & 31; // B-load float4 index along N

    for (int k0 = 0; k0 < Kd; k0 += BK) {
        // Stage A tile transposed: As[kk][m]
#pragma unroll
        for (int i = 0; i < 2; i++) {
            int r = ar + 64 * i;
            const float4 av = *(const float4*)(A + (size_t)(m0 + r) * Kd + k0 + 4 * ac4);
            As[4 * ac4 + 0][r] = av.x;
            As[4 * ac4 + 1][r] = av.y;
            As[4 * ac4 + 2][r] = av.z;
            As[4 * ac4 + 3][r] = av.w;
        }
        // Stage B tile: Bs[kk][n] (zero-fill out-of-range cols; stores are guarded)
#pragma unroll
        for (int i = 0; i < 2; i++) {
            int kr = bkr + 8 * i;
            int col = n0 + 4 * bc32;
            float4 bv;
            if (col + 3 < N) bv = *(const float4*)(Bw + (size_t)(k0 + kr) * N + col);
            else             bv = make_float4(0.f, 0.f, 0.f, 0.f);
            *(float4*)&Bs[kr][4 * bc32] = bv;
        }
        __syncthreads();

#pragma unroll
        for (int kk = 0; kk < BK; kk++) {
            float a[TM], bf[TN];
#pragma unroll
            for (int j4 = 0; j4 < 4; j4++)
                *(float4*)&a[4 * j4] = *(const float4*)&As[kk][ty * TM + 4 * j4];
            *(float4*)&bf[0] = *(const float4*)&Bs[kk][tx * TN];
#pragma unroll
            for (int i = 0; i < TM; i++)
#pragma unroll
                for (int j = 0; j < TN; j++)
                    acc[i][j] = fmaf(a[i], bf[j], acc[i][j]);
        }
        __syncthreads();
    }

    // Epilogue: bias (+ReLU), coalesced float4 stores
    const int coln = n0 + tx * TN;
    float bv[TN];
#pragma unroll
    for (int j = 0; j < TN; j++) {
        int col = coln + j;
        bv[j] = (col < N) ? bias[col] : 0.f;
    }
#pragma unroll
    for (int i = 0; i < TM; i++) {
        int row = m0 + ty * TM + i;
        float4 v;
        v.x = acc[i][0] + bv[0];
        v.y = acc[i][1] + bv[1];
        v.z = acc[i][2] + bv[2];
        v.w = acc[i][3] + bv[3];
        if (relu) {
            v.x = fmaxf(v.x, 0.f); v.y = fmaxf(v.y, 0.f);
            v.z = fmaxf(v.z, 0.f); v.w = fmaxf(v.w, 0.f);
        }
        if (coln + 3 < N) {
            *(float4*)(Cc + (size_t)row * N + coln) = v;
        } else {
            float vv[4] = {v.x, v.y, v.z, v.w};
            for (int j = 0; j < TN; j++)
                if (coln + j < N) Cc[(size_t)row * N + coln + j] = vv[j];
        }
    }
}

// ---------------- per-sample softmax + greedy expert selection + combine ----------------
// L: [K][Bc][C] chunk of logits_all. One block (256 thr) per sample.
__global__ __launch_bounds__(256) void gate_combine(
    const float* __restrict__ L,
    const int* __restrict__ n_exp,
    float* __restrict__ out_logits,   // [Bc][C] (already offset)
    float* __restrict__ out_gates,    // [Bc][K] (already offset)
    int Bc)
{
    const int b = blockIdx.x;
    const int tid = threadIdx.x;
    const int lane = tid & 63;
    const int wv = tid >> 6;

    __shared__ float sl[K_EXP][C_DIM];        // 32000 B
    __shared__ float wred[4][40];
    __shared__ float m_s[K_EXP], z_s[K_EXP];
    __shared__ float d_s[36];
    __shared__ float S_s[K_EXP][K_EXP];
    __shared__ float conf_s[K_EXP];
    __shared__ float gates_s[K_EXP];

    const size_t kc_stride = (size_t)Bc * C_DIM;

    // Phase 1: load logits -> LDS, per-expert max
    float mx[K_EXP];
#pragma unroll
    for (int k = 0; k < K_EXP; k++) mx[k] = -INFINITY;
    for (int c = tid; c < C_DIM; c += 256) {
#pragma unroll
        for (int k = 0; k < K_EXP; k++) {
            float v = L[(size_t)k * kc_stride + (size_t)b * C_DIM + c];
            sl[k][c] = v;
            mx[k] = fmaxf(mx[k], v);
        }
    }
#pragma unroll
    for (int k = 0; k < K_EXP; k++)
#pragma unroll
        for (int off = 32; off > 0; off >>= 1)
            mx[k] = fmaxf(mx[k], __shfl_xor(mx[k], off, 64));
    if (lane == 0)
#pragma unroll
        for (int k = 0; k < K_EXP; k++) wred[wv][k] = mx[k];
    __syncthreads();
    if (tid < K_EXP) {
        float m = wred[0][tid];
        for (int w = 1; w < 4; w++) m = fmaxf(m, wred[w][tid]);
        m_s[tid] = m;
    }
    __syncthreads();

    // Phase 2: softmax denominators Z_k
    float zs[K_EXP];
#pragma unroll
    for (int k = 0; k < K_EXP; k++) zs[k] = 0.f;
    for (int c = tid; c < C_DIM; c += 256) {
#pragma unroll
        for (int k = 0; k < K_EXP; k++)
            zs[k] += __expf(sl[k][c] - m_s[k]);
    }
#pragma unroll
    for (int k = 0; k < K_EXP; k++)
#pragma unroll
        for (int off = 32; off > 0; off >>= 1)
            zs[k] += __shfl_xor(zs[k], off, 64);
    if (lane == 0)
#pragma unroll
        for (int k = 0; k < K_EXP; k++) wred[wv][k] = zs[k];
    __syncthreads();
    if (tid < K_EXP) {
        float z = 0.f;
        for (int w = 0; w < 4; w++) z += wred[w][tid];
        z_s[tid] = z;
    }
    __syncthreads();

    // Phase 3: 36 pairwise dots of unnormalized probs e_i = exp(l - m)
    float dd[36];
#pragma unroll
    for (int p = 0; p < 36; p++) dd[p] = 0.f;
    for (int c = tid; c < C_DIM; c += 256) {
        float e[K_EXP];
#pragma unroll
        for (int k = 0; k < K_EXP; k++)
            e[k] = __expf(sl[k][c] - m_s[k]);
        int idx = 0;
#pragma unroll
        for (int i = 0; i < K_EXP; i++)
#pragma unroll
            for (int j = i; j < K_EXP; j++)
                dd[idx++] = fmaf(e[i], e[j], dd[idx]);
    }
#pragma unroll
    for (int p = 0; p < 36; p++)
#pragma unroll
        for (int off = 32; off > 0; off >>= 1)
            dd[p] += __shfl_xor(dd[p], off, 64);
    if (lane == 0)
#pragma unroll
        for (int p = 0; p < 36; p++) wred[wv][p] = dd[p];
    __syncthreads();
    if (tid < 36) {
        float s = 0.f;
        for (int w = 0; w < 4; w++) s += wred[w][tid];
        d_s[tid] = s;
    }
    __syncthreads();

    // Phase 4: serial gating (K=8 is tiny) — exactly mirrors reference semantics
    if (tid == 0) {
        // unpack E_ij, cosine sims
        int idx = 0;
        for (int i = 0; i < K_EXP; i++)
            for (int j = i; j < K_EXP; j++) {
                S_s[i][j] = d_s[idx];
                S_s[j][i] = d_s[idx];
                idx++;
            }
        float nrm[K_EXP];
#pragma unroll
        for (int k = 0; k < K_EXP; k++) {
            conf_s[k] = 1.0f / z_s[k];                 // max(softmax) = 1/Z
            nrm[k] = sqrtf(S_s[k][k]) / z_s[k];        // ||p_k||
        }
        for (int i = 0; i < K_EXP; i++)
            for (int j = 0; j < K_EXP; j++)
                S_s[i][j] = (S_s[i][j] / (z_s[i] * z_s[j])) /
                            ((nrm[i] + EPS_N) * (nrm[j] + EPS_N));

        // sel0 = argmax conf (first occurrence)
        int i0 = 0; float bcf = conf_s[0];
        for (int k = 1; k < K_EXP; k++)
            if (conf_s[k] > bcf) { bcf = conf_s[k]; i0 = k; }
        unsigned sel = 1u << i0;
        const int n = n_exp[b];

        for (int t = 1; t < K_EXP; t++) {
            float bd = -INFINITY; int bi = 0; int found = 0;
            for (int i = 0; i < K_EXP; i++) {
                if (sel & (1u << i)) continue;          // dist = -inf in reference
                float ms = -INFINITY;
                for (int j = 0; j < K_EXP; j++)
                    if (sel & (1u << j)) ms = fmaxf(ms, S_s[i][j]);
                float dist = 1.0f - ms;
                if (!found || dist > bd) { bd = dist; bi = i; found = 1; }
            }
            if (t < n) sel |= 1u << bi;
        }

        float cmax = -INFINITY;
        for (int k = 0; k < K_EXP; k++)
            if (sel & (1u << k)) cmax = fmaxf(cmax, conf_s[k]);
        float gsum = 0.f, g[K_EXP];
        for (int k = 0; k < K_EXP; k++) {
            g[k] = (sel & (1u << k)) ? __expf((conf_s[k] - cmax) * TEMP_INV) : 0.f;
            gsum += g[k];
        }
        for (int k = 0; k < K_EXP; k++) {
            float gv = g[k] / gsum;
            gates_s[k] = gv;
            out_gates[(size_t)b * K_EXP + k] = gv;
        }
    }
    __syncthreads();

    // Phase 5: gated combine straight from LDS
    for (int c = tid; c < C_DIM; c += 256) {
        float o = 0.f;
#pragma unroll
        for (int k = 0; k < K_EXP; k++)
            o = fmaf(gates_s[k], sl[k][c], o);
        out_logits[(size_t)b * C_DIM + c] = o;
    }
}

// ---------------- launch ----------------
extern "C" void kernel_launch(void* const* d_in, const int* in_sizes, int n_in,
                              void* d_out, int out_size, void* d_ws, size_t ws_size,
                              hipStream_t stream) {
    const float* z     = (const float*)d_in[0];
    const int*   n_exp = (const int*)d_in[1];
    const float* W1    = (const float*)d_in[2];
    const float* b1    = (const float*)d_in[3];
    const float* W2    = (const float*)d_in[4];
    const float* b2    = (const float*)d_in[5];
    float* out_logits = (float*)d_out;                       // [B, C]
    float* out_gates  = (float*)d_out + (size_t)B_SZ * C_DIM; // [B, K]

    // Adaptive batch chunking so ws fits: per chunk need K*Bc*(D+C)*4 bytes.
    int nch = 1;
    while (nch < 16) {
        size_t bc = B_SZ / nch;
        if ((size_t)K_EXP * bc * (D_DIM + C_DIM) * 4 <= ws_size) break;
        nch *= 2;
    }
    const int Bc = B_SZ / nch;

    float* h  = (float*)d_ws;                                 // [K][Bc][D]
    float* Lb = h + (size_t)K_EXP * Bc * D_DIM;               // [K][Bc][C]

    for (int ch = 0; ch < nch; ch++) {
        const int off = ch * Bc;
        const float* zc = z + (size_t)off * D_DIM;

        dim3 g1(D_DIM / BN, Bc / BM, K_EXP);
        gemm_bias_act<<<g1, 256, 0, stream>>>(
            zc, 0LL,
            W1, (long long)D_DIM * D_DIM,
            b1, D_DIM,
            h, (long long)Bc * D_DIM,
            Bc, D_DIM, D_DIM, 1);

        dim3 g2((C_DIM + BN - 1) / BN, Bc / BM, K_EXP);
        gemm_bias_act<<<g2, 256, 0, stream>>>(
            h, (long long)Bc * D_DIM,
            W2, (long long)D_DIM * C_DIM,
            b2, C_DIM,
            Lb, (long long)Bc * C_DIM,
            Bc, C_DIM, D_DIM, 0);

        gate_combine<<<dim3(Bc), 256, 0, stream>>>(
            Lb, n_exp + off,
            out_logits + (size_t)off * C_DIM,
            out_gates + (size_t)off * K_EXP,
            Bc);
    }
}

// Round 2
// 1042.300 us; speedup vs baseline: 1.4952x; 1.4952x over previous
//
#include <hip/hip_runtime.h>
#include <math.h>

#define B_SZ 8192
#define D_DIM 512
#define C_DIM 1000
#define C_PAD 1024
#define K_EXP 8
#define TEMP_INV 5.0f
#define EPS_N 1e-8f

typedef __attribute__((ext_vector_type(8))) short frag_ab;
typedef __attribute__((ext_vector_type(4))) float frag_cd;

__device__ __forceinline__ short f2bf(float f) {
    unsigned u = __builtin_bit_cast(unsigned, f);
    unsigned r = (u + 0x7fffu + ((u >> 16) & 1u)) >> 16;
    return (short)r;
}
__device__ __forceinline__ float bf2f(short s) {
    unsigned u = ((unsigned)(unsigned short)s) << 16;
    return __builtin_bit_cast(float, u);
}
__device__ __forceinline__ void split3(float v, short& s0, short& s1, short& s2) {
    s0 = f2bf(v);
    float r1 = v - bf2f(s0);
    s1 = f2bf(r1);
    float r2 = r1 - bf2f(s1);
    s2 = f2bf(r2);
}

// async global->LDS, 16B per lane. LDS dest must be wave-contiguous (base + lane*16).
__device__ __forceinline__ void gl_lds16(const short* g, short* l) {
    __builtin_amdgcn_global_load_lds(
        (const __attribute__((address_space(1))) unsigned int*)(const void*)g,
        (__attribute__((address_space(3))) unsigned int*)(void*)l,
        16, 0, 0);
}

// ---------------- one-time prep: transpose + 3-way bf16 split ----------------
__global__ __launch_bounds__(256) void prep_z(const float* __restrict__ z,
                                              short* __restrict__ p0, short* __restrict__ p1,
                                              short* __restrict__ p2) {
    int idx = blockIdx.x * 256 + threadIdx.x;   // B_SZ*D_DIM = 4194304
    float v = z[idx];
    short a, b, c; split3(v, a, b, c);
    p0[idx] = a; p1[idx] = b; p2[idx] = c;
}

// W1 [K][d][e] -> W1t [K][e][d]
__global__ __launch_bounds__(256) void prep_w1(const float* __restrict__ W1,
                                               short* __restrict__ p0, short* __restrict__ p1,
                                               short* __restrict__ p2) {
    int idx = blockIdx.x * 256 + threadIdx.x;   // 8*512*512 = 2097152
    int k = idx >> 18;
    int e = (idx >> 9) & 511;
    int d = idx & 511;
    float v = W1[((size_t)k << 18) + (size_t)d * 512 + e];
    short a, b, c; split3(v, a, b, c);
    p0[idx] = a; p1[idx] = b; p2[idx] = c;
}

// W2 [K][e][c] -> W2t [K][C_PAD][e], zero-padded rows c>=1000
__global__ __launch_bounds__(256) void prep_w2(const float* __restrict__ W2,
                                               short* __restrict__ p0, short* __restrict__ p1,
                                               short* __restrict__ p2) {
    int idx = blockIdx.x * 256 + threadIdx.x;   // 8*1024*512 = 4194304
    int k = idx >> 19;
    int c = (idx >> 9) & 1023;
    int e = idx & 511;
    float v = (c < C_DIM) ? W2[(size_t)k * (D_DIM * C_DIM) + (size_t)e * C_DIM + c] : 0.f;
    short a, b, cc; split3(v, a, b, cc);
    p0[idx] = a; p1[idx] = b; p2[idx] = cc;
}

// ---------------- split-bf16 MFMA GEMM: 128x128x32 tile, 6 products ----------------
// A planes: [M][512] bf16 row-major (per-expert stride aBatch elements; 0 = shared)
// B planes: [N][512] bf16 row-major (= weights transposed), N multiple of 128
// mode 0: Cf = acc + bias (fp32, guard col<Nout, row stride ldc)
// mode 1: h planes = split3(relu(acc + bias)), row stride 512
__global__ __launch_bounds__(256, 2) void gemm_split(
    const short* __restrict__ A0, const short* __restrict__ A1, const short* __restrict__ A2,
    long long aBatch,
    const short* __restrict__ B0, const short* __restrict__ B1, const short* __restrict__ B2,
    long long bBatch,
    const float* __restrict__ bias, int biasBatch,
    float* __restrict__ Cf, long long cBatch, int ldc, int Nout,
    short* __restrict__ H0, short* __restrict__ H1, short* __restrict__ H2,
    long long hBatch, int mode)
{
    const int k = blockIdx.z;
    const int m0 = blockIdx.y * 128;
    const int n0 = blockIdx.x * 128;
    const int tid = threadIdx.x;
    const int lane = tid & 63;
    const int wv = tid >> 6;
    const int wm = (wv & 1) * 64;   // wave tile row origin within block
    const int wn = (wv >> 1) * 64;  // wave tile col origin

    __shared__ short lds[24576];    // A planes: 3*4096 shorts; B planes: 3*4096

    const short* gA0 = A0 + (size_t)k * aBatch + (size_t)m0 * 512;
    const short* gA1 = A1 + (size_t)k * aBatch + (size_t)m0 * 512;
    const short* gA2 = A2 + (size_t)k * aBatch + (size_t)m0 * 512;
    const short* gB0 = B0 + (size_t)k * bBatch + (size_t)n0 * 512;
    const short* gB1 = B1 + (size_t)k * bBatch + (size_t)n0 * 512;
    const short* gB2 = B2 + (size_t)k * bBatch + (size_t)n0 * 512;
    short* ldsA = lds;
    short* ldsB = lds + 12288;

    frag_cd acc[4][4];
#pragma unroll
    for (int i = 0; i < 4; i++)
#pragma unroll
        for (int j = 0; j < 4; j++)
            acc[i][j] = (frag_cd){0.f, 0.f, 0.f, 0.f};

    const int srow = tid >> 2;      // 0..63
    const int sch  = (tid & 3) * 8; // chunk offset in elements (16B)

    for (int k0 = 0; k0 < 512; k0 += 32) {
        // stage 3 A planes + 3 B planes (48 KB) via width-16 global_load_lds
        const short* ga[3] = {gA0, gA1, gA2};
        const short* gb[3] = {gB0, gB1, gB2};
#pragma unroll
        for (int p = 0; p < 3; p++) {
#pragma unroll
            for (int hh = 0; hh < 2; hh++) {
                int row = hh * 64 + srow;
                gl_lds16(ga[p] + (size_t)row * 512 + k0 + sch,
                         ldsA + p * 4096 + row * 32 + sch);
                gl_lds16(gb[p] + (size_t)row * 512 + k0 + sch,
                         ldsB + p * 4096 + row * 32 + sch);
            }
        }
        __syncthreads();   // drains vmcnt (incl. global_load_lds) then barrier

        // LDS -> fragments: A[m=lane&15][k=(lane>>4)*8+j], B[n=lane&15][k=(lane>>4)*8+j]
        frag_ab af[3][4], bfr[3][4];
#pragma unroll
        for (int p = 0; p < 3; p++)
#pragma unroll
            for (int t = 0; t < 4; t++) {
                af[p][t]  = *(const frag_ab*)(ldsA + p * 4096 + (wm + t * 16 + (lane & 15)) * 32 + (lane >> 4) * 8);
                bfr[p][t] = *(const frag_ab*)(ldsB + p * 4096 + (wn + t * 16 + (lane & 15)) * 32 + (lane >> 4) * 8);
            }

#pragma unroll
        for (int i = 0; i < 4; i++)
#pragma unroll
            for (int j = 0; j < 4; j++) {
                frag_cd c = acc[i][j];
                c = __builtin_amdgcn_mfma_f32_16x16x32_bf16(af[0][i], bfr[0][j], c, 0, 0, 0);
                c = __builtin_amdgcn_mfma_f32_16x16x32_bf16(af[0][i], bfr[1][j], c, 0, 0, 0);
                c = __builtin_amdgcn_mfma_f32_16x16x32_bf16(af[1][i], bfr[0][j], c, 0, 0, 0);
                c = __builtin_amdgcn_mfma_f32_16x16x32_bf16(af[1][i], bfr[1][j], c, 0, 0, 0);
                c = __builtin_amdgcn_mfma_f32_16x16x32_bf16(af[0][i], bfr[2][j], c, 0, 0, 0);
                c = __builtin_amdgcn_mfma_f32_16x16x32_bf16(af[2][i], bfr[0][j], c, 0, 0, 0);
                acc[i][j] = c;
            }
        __syncthreads();
    }

    // epilogue: C/D layout col=lane&15, row=(lane>>4)*4+reg
    const int r0 = (lane >> 4) * 4;
    const int cc = lane & 15;
    if (mode == 0) {
        float* C = Cf + (size_t)k * cBatch;
        const float* bb = bias + (size_t)k * biasBatch;
#pragma unroll
        for (int i = 0; i < 4; i++) {
            int rowb = m0 + wm + i * 16 + r0;
#pragma unroll
            for (int j = 0; j < 4; j++) {
                int col = n0 + wn + j * 16 + cc;
                if (col < Nout) {
                    float b = bb[col];
#pragma unroll
                    for (int r = 0; r < 4; r++)
                        C[(size_t)(rowb + r) * ldc + col] = acc[i][j][r] + b;
                }
            }
        }
    } else {
        short* h0 = H0 + (size_t)k * hBatch;
        short* h1 = H1 + (size_t)k * hBatch;
        short* h2 = H2 + (size_t)k * hBatch;
        const float* bb = bias + (size_t)k * biasBatch;
#pragma unroll
        for (int i = 0; i < 4; i++) {
            int rowb = m0 + wm + i * 16 + r0;
#pragma unroll
            for (int j = 0; j < 4; j++) {
                int col = n0 + wn + j * 16 + cc;
                float b = bb[col];
#pragma unroll
                for (int r = 0; r < 4; r++) {
                    float v = fmaxf(acc[i][j][r] + b, 0.f);
                    short s0, s1, s2; split3(v, s0, s1, s2);
                    size_t o = (size_t)(rowb + r) * 512 + col;
                    h0[o] = s0; h1[o] = s1; h2[o] = s2;
                }
            }
        }
    }
}

// ---------------- per-sample softmax + greedy expert selection + combine ----------------
__global__ __launch_bounds__(256) void gate_combine(
    const float* __restrict__ L,      // [K][Bc][C]
    const int* __restrict__ n_exp,
    float* __restrict__ out_logits,   // [Bc][C] (already offset)
    float* __restrict__ out_gates,    // [Bc][K] (already offset)
    int Bc)
{
    const int b = blockIdx.x;
    const int tid = threadIdx.x;
    const int lane = tid & 63;
    const int wv = tid >> 6;

    __shared__ float sl[K_EXP][C_DIM];
    __shared__ float wred[4][40];
    __shared__ float m_s[K_EXP], z_s[K_EXP];
    __shared__ float d_s[36];
    __shared__ float S_s[K_EXP][K_EXP];
    __shared__ float conf_s[K_EXP];
    __shared__ float gates_s[K_EXP];

    const size_t kc_stride = (size_t)Bc * C_DIM;

    float mx[K_EXP];
#pragma unroll
    for (int k = 0; k < K_EXP; k++) mx[k] = -INFINITY;
    for (int c = tid; c < C_DIM; c += 256) {
#pragma unroll
        for (int k = 0; k < K_EXP; k++) {
            float v = L[(size_t)k * kc_stride + (size_t)b * C_DIM + c];
            sl[k][c] = v;
            mx[k] = fmaxf(mx[k], v);
        }
    }
#pragma unroll
    for (int k = 0; k < K_EXP; k++)
#pragma unroll
        for (int off = 32; off > 0; off >>= 1)
            mx[k] = fmaxf(mx[k], __shfl_xor(mx[k], off, 64));
    if (lane == 0)
#pragma unroll
        for (int k = 0; k < K_EXP; k++) wred[wv][k] = mx[k];
    __syncthreads();
    if (tid < K_EXP) {
        float m = wred[0][tid];
        for (int w = 1; w < 4; w++) m = fmaxf(m, wred[w][tid]);
        m_s[tid] = m;
    }
    __syncthreads();

    float zs[K_EXP];
#pragma unroll
    for (int k = 0; k < K_EXP; k++) zs[k] = 0.f;
    for (int c = tid; c < C_DIM; c += 256) {
#pragma unroll
        for (int k = 0; k < K_EXP; k++)
            zs[k] += __expf(sl[k][c] - m_s[k]);
    }
#pragma unroll
    for (int k = 0; k < K_EXP; k++)
#pragma unroll
        for (int off = 32; off > 0; off >>= 1)
            zs[k] += __shfl_xor(zs[k], off, 64);
    if (lane == 0)
#pragma unroll
        for (int k = 0; k < K_EXP; k++) wred[wv][k] = zs[k];
    __syncthreads();
    if (tid < K_EXP) {
        float z = 0.f;
        for (int w = 0; w < 4; w++) z += wred[w][tid];
        z_s[tid] = z;
    }
    __syncthreads();

    float dd[36];
#pragma unroll
    for (int p = 0; p < 36; p++) dd[p] = 0.f;
    for (int c = tid; c < C_DIM; c += 256) {
        float e[K_EXP];
#pragma unroll
        for (int k = 0; k < K_EXP; k++)
            e[k] = __expf(sl[k][c] - m_s[k]);
        int idx = 0;
#pragma unroll
        for (int i = 0; i < K_EXP; i++)
#pragma unroll
            for (int j = i; j < K_EXP; j++) {
                dd[idx] = fmaf(e[i], e[j], dd[idx]);
                idx++;
            }
    }
#pragma unroll
    for (int p = 0; p < 36; p++)
#pragma unroll
        for (int off = 32; off > 0; off >>= 1)
            dd[p] += __shfl_xor(dd[p], off, 64);
    if (lane == 0)
#pragma unroll
        for (int p = 0; p < 36; p++) wred[wv][p] = dd[p];
    __syncthreads();
    if (tid < 36) {
        float s = 0.f;
        for (int w = 0; w < 4; w++) s += wred[w][tid];
        d_s[tid] = s;
    }
    __syncthreads();

    if (tid == 0) {
        int idx = 0;
        for (int i = 0; i < K_EXP; i++)
            for (int j = i; j < K_EXP; j++) {
                S_s[i][j] = d_s[idx];
                S_s[j][i] = d_s[idx];
                idx++;
            }
        float nrm[K_EXP];
#pragma unroll
        for (int k = 0; k < K_EXP; k++) {
            conf_s[k] = 1.0f / z_s[k];
            nrm[k] = sqrtf(S_s[k][k]) / z_s[k];
        }
        for (int i = 0; i < K_EXP; i++)
            for (int j = 0; j < K_EXP; j++)
                S_s[i][j] = (S_s[i][j] / (z_s[i] * z_s[j])) /
                            ((nrm[i] + EPS_N) * (nrm[j] + EPS_N));

        int i0 = 0; float bcf = conf_s[0];
        for (int k = 1; k < K_EXP; k++)
            if (conf_s[k] > bcf) { bcf = conf_s[k]; i0 = k; }
        unsigned sel = 1u << i0;
        const int n = n_exp[b];

        for (int t = 1; t < K_EXP; t++) {
            float bd = -INFINITY; int bi = 0; int found = 0;
            for (int i = 0; i < K_EXP; i++) {
                if (sel & (1u << i)) continue;
                float ms = -INFINITY;
                for (int j = 0; j < K_EXP; j++)
                    if (sel & (1u << j)) ms = fmaxf(ms, S_s[i][j]);
                float dist = 1.0f - ms;
                if (!found || dist > bd) { bd = dist; bi = i; found = 1; }
            }
            if (t < n) sel |= 1u << bi;
        }

        float cmax = -INFINITY;
        for (int k = 0; k < K_EXP; k++)
            if (sel & (1u << k)) cmax = fmaxf(cmax, conf_s[k]);
        float gsum = 0.f, g[K_EXP];
        for (int k = 0; k < K_EXP; k++) {
            g[k] = (sel & (1u << k)) ? __expf((conf_s[k] - cmax) * TEMP_INV) : 0.f;
            gsum += g[k];
        }
        for (int k = 0; k < K_EXP; k++) {
            float gv = g[k] / gsum;
            gates_s[k] = gv;
            out_gates[(size_t)b * K_EXP + k] = gv;
        }
    }
    __syncthreads();

    for (int c = tid; c < C_DIM; c += 256) {
        float o = 0.f;
#pragma unroll
        for (int k = 0; k < K_EXP; k++)
            o = fmaf(gates_s[k], sl[k][c], o);
        out_logits[(size_t)b * C_DIM + c] = o;
    }
}

// ---------------- launch ----------------
extern "C" void kernel_launch(void* const* d_in, const int* in_sizes, int n_in,
                              void* d_out, int out_size, void* d_ws, size_t ws_size,
                              hipStream_t stream) {
    const float* z     = (const float*)d_in[0];
    const int*   n_exp = (const int*)d_in[1];
    const float* W1    = (const float*)d_in[2];
    const float* b1    = (const float*)d_in[3];
    const float* W2    = (const float*)d_in[4];
    const float* b2    = (const float*)d_in[5];
    float* out_logits = (float*)d_out;
    float* out_gates  = (float*)d_out + (size_t)B_SZ * C_DIM;

    // ws layout (bytes)
    const size_t zP   = (size_t)B_SZ * D_DIM * 2;          // 8 MB per plane
    const size_t w1P  = (size_t)K_EXP * D_DIM * D_DIM * 2; // 4 MB per plane
    const size_t w2P  = (size_t)K_EXP * C_PAD * D_DIM * 2; // 8 MB per plane
    const size_t fixedBytes = 3 * (zP + w1P + w2P);        // 62.9 MB

    // chunking: per chunk need Bc*(3*8192 [h planes] + 32000 [fp32 logits]) bytes
    int nch = 1;
    while (nch < 32 && fixedBytes + (size_t)(B_SZ / nch) * 56576 > ws_size) nch *= 2;
    const int Bc = B_SZ / nch;

    char* w = (char*)d_ws;
    short* zp[3];  zp[0]  = (short*)w;            zp[1]  = (short*)(w + zP);  zp[2]  = (short*)(w + 2*zP);  w += 3*zP;
    short* w1t[3]; w1t[0] = (short*)w;            w1t[1] = (short*)(w + w1P); w1t[2] = (short*)(w + 2*w1P); w += 3*w1P;
    short* w2t[3]; w2t[0] = (short*)w;            w2t[1] = (short*)(w + w2P); w2t[2] = (short*)(w + 2*w2P); w += 3*w2P;
    const size_t hP = (size_t)K_EXP * Bc * D_DIM * 2;      // h plane bytes
    short* hp[3];  hp[0]  = (short*)w;            hp[1]  = (short*)(w + hP);  hp[2]  = (short*)(w + 2*hP);  w += 3*hP;
    float* Lb = (float*)w;                                  // [K][Bc][C] fp32

    // one-time prep (inside timed region; ~60 MB traffic)
    prep_z <<<dim3((B_SZ * D_DIM) / 256), 256, 0, stream>>>(z, zp[0], zp[1], zp[2]);
    prep_w1<<<dim3((K_EXP * D_DIM * D_DIM) / 256), 256, 0, stream>>>(W1, w1t[0], w1t[1], w1t[2]);
    prep_w2<<<dim3((K_EXP * C_PAD * D_DIM) / 256), 256, 0, stream>>>(W2, w2t[0], w2t[1], w2t[2]);

    for (int ch = 0; ch < nch; ch++) {
        const int off = ch * Bc;
        const long long zoff = (long long)off * D_DIM;

        // GEMM1: h = relu(z @ W1 + b1), output as 3 bf16 planes
        dim3 g1(D_DIM / 128, Bc / 128, K_EXP);
        gemm_split<<<g1, 256, 0, stream>>>(
            zp[0] + zoff, zp[1] + zoff, zp[2] + zoff, 0LL,
            w1t[0], w1t[1], w1t[2], (long long)D_DIM * D_DIM,
            b1, D_DIM,
            nullptr, 0LL, 0, D_DIM,
            hp[0], hp[1], hp[2], (long long)Bc * D_DIM,
            1);

        // GEMM2: logits = h @ W2 + b2 (fp32 out)
        dim3 g2(C_PAD / 128, Bc / 128, K_EXP);
        gemm_split<<<g2, 256, 0, stream>>>(
            hp[0], hp[1], hp[2], (long long)Bc * D_DIM,
            w2t[0], w2t[1], w2t[2], (long long)C_PAD * D_DIM,
            b2, C_DIM,
            Lb, (long long)Bc * C_DIM, C_DIM, C_DIM,
            nullptr, nullptr, nullptr, 0LL,
            0);

        gate_combine<<<dim3(Bc), 256, 0, stream>>>(
            Lb, n_exp + off,
            out_logits + (size_t)off * C_DIM,
            out_gates + (size_t)off * K_EXP,
            Bc);
    }
}

// Round 3
// 693.845 us; speedup vs baseline: 2.2462x; 1.5022x over previous
//
#include <hip/hip_runtime.h>
#include <math.h>

#define B_SZ 8192
#define D_DIM 512
#define C_DIM 1000
#define C_PAD 1024
#define K_EXP 8
#define TEMP_INV 5.0f
#define EPS_N 1e-8f

typedef __attribute__((ext_vector_type(8))) short frag_ab;
typedef __attribute__((ext_vector_type(4))) float frag_cd;

__device__ __forceinline__ short f2bf(float f) {
    unsigned u = __builtin_bit_cast(unsigned, f);
    unsigned r = (u + 0x7fffu + ((u >> 16) & 1u)) >> 16;
    return (short)r;
}
__device__ __forceinline__ float bf2f(short s) {
    unsigned u = ((unsigned)(unsigned short)s) << 16;
    return __builtin_bit_cast(float, u);
}
// 2-plane split: v ~= s0 + s1, |residual| ~ 2^-18 |v|
__device__ __forceinline__ void split2(float v, short& s0, short& s1) {
    s0 = f2bf(v);
    s1 = f2bf(v - bf2f(s0));
}

// async global->LDS, 16B per lane (LDS dest wave-contiguous: base + lane*16)
__device__ __forceinline__ void gl_lds16(const short* g, short* l) {
    __builtin_amdgcn_global_load_lds(
        (const __attribute__((address_space(1))) unsigned int*)(const void*)g,
        (__attribute__((address_space(3))) unsigned int*)(void*)l,
        16, 0, 0);
}

// ---------------- one-time prep: transpose + 2-way bf16 split ----------------
__global__ __launch_bounds__(256) void prep_z(const float* __restrict__ z,
                                              short* __restrict__ p0, short* __restrict__ p1) {
    int idx = blockIdx.x * 256 + threadIdx.x;   // B_SZ*D_DIM
    float v = z[idx];
    short a, b; split2(v, a, b);
    p0[idx] = a; p1[idx] = b;
}

// W1 [K][d][e] -> W1t [K][e][d]
__global__ __launch_bounds__(256) void prep_w1(const float* __restrict__ W1,
                                               short* __restrict__ p0, short* __restrict__ p1) {
    int idx = blockIdx.x * 256 + threadIdx.x;   // 8*512*512
    int k = idx >> 18;
    int e = (idx >> 9) & 511;
    int d = idx & 511;
    float v = W1[((size_t)k << 18) + (size_t)d * 512 + e];
    short a, b; split2(v, a, b);
    p0[idx] = a; p1[idx] = b;
}

// W2 [K][e][c] -> W2t [K][C_PAD][e], zero rows c>=1000
__global__ __launch_bounds__(256) void prep_w2(const float* __restrict__ W2,
                                               short* __restrict__ p0, short* __restrict__ p1) {
    int idx = blockIdx.x * 256 + threadIdx.x;   // 8*1024*512
    int k = idx >> 19;
    int c = (idx >> 9) & 1023;
    int e = idx & 511;
    float v = (c < C_DIM) ? W2[(size_t)k * (D_DIM * C_DIM) + (size_t)e * C_DIM + c] : 0.f;
    short a, b; split2(v, a, b);
    p0[idx] = a; p1[idx] = b;
}

// ---------------- split-bf16 MFMA GEMM: 128x128x32 tile, 3 products ----------------
// A planes: [M][512] bf16 row-major (per-expert stride aBatch; 0 = shared)
// B planes: [N][512] bf16 row-major (weights transposed), N multiple of 128
// mode 0: Cf = acc + bias (fp32, guard col<Nout, row stride ldc)
// mode 1: h planes = split2(relu(acc + bias)), row stride 512
__global__ __launch_bounds__(256, 3) void gemm_split(
    const short* __restrict__ A0, const short* __restrict__ A1, long long aBatch,
    const short* __restrict__ B0, const short* __restrict__ B1, long long bBatch,
    const float* __restrict__ bias, int biasBatch,
    float* __restrict__ Cf, long long cBatch, int ldc, int Nout,
    short* __restrict__ H0, short* __restrict__ H1, long long hBatch, int mode)
{
    const int k = blockIdx.z;
    const int m0 = blockIdx.y * 128;
    const int n0 = blockIdx.x * 128;
    const int tid = threadIdx.x;
    const int lane = tid & 63;
    const int wv = tid >> 6;
    const int wm = (wv & 1) * 64;
    const int wn = (wv >> 1) * 64;

    __shared__ short lds[16384];    // A0,A1: 2*4096 shorts; B0,B1: 2*4096 (32 KB)

    const short* gA0 = A0 + (size_t)k * aBatch + (size_t)m0 * 512;
    const short* gA1 = A1 + (size_t)k * aBatch + (size_t)m0 * 512;
    const short* gB0 = B0 + (size_t)k * bBatch + (size_t)n0 * 512;
    const short* gB1 = B1 + (size_t)k * bBatch + (size_t)n0 * 512;
    short* ldsA = lds;
    short* ldsB = lds + 8192;

    frag_cd acc[4][4];
#pragma unroll
    for (int i = 0; i < 4; i++)
#pragma unroll
        for (int j = 0; j < 4; j++)
            acc[i][j] = (frag_cd){0.f, 0.f, 0.f, 0.f};

    const int srow = tid >> 2;      // 0..63
    const int sch  = (tid & 3) * 8; // 16B chunk offset in elements

    for (int k0 = 0; k0 < 512; k0 += 32) {
        const short* ga[2] = {gA0, gA1};
        const short* gb[2] = {gB0, gB1};
#pragma unroll
        for (int p = 0; p < 2; p++) {
#pragma unroll
            for (int hh = 0; hh < 2; hh++) {
                int row = hh * 64 + srow;
                gl_lds16(ga[p] + (size_t)row * 512 + k0 + sch,
                         ldsA + p * 4096 + row * 32 + sch);
                gl_lds16(gb[p] + (size_t)row * 512 + k0 + sch,
                         ldsB + p * 4096 + row * 32 + sch);
            }
        }
        __syncthreads();

        // fragments: A[m=lane&15][k=(lane>>4)*8+j]
        frag_ab af[2][4], bfr[2][4];
#pragma unroll
        for (int p = 0; p < 2; p++)
#pragma unroll
            for (int t = 0; t < 4; t++) {
                af[p][t]  = *(const frag_ab*)(ldsA + p * 4096 + (wm + t * 16 + (lane & 15)) * 32 + (lane >> 4) * 8);
                bfr[p][t] = *(const frag_ab*)(ldsB + p * 4096 + (wn + t * 16 + (lane & 15)) * 32 + (lane >> 4) * 8);
            }

#pragma unroll
        for (int i = 0; i < 4; i++)
#pragma unroll
            for (int j = 0; j < 4; j++) {
                frag_cd c = acc[i][j];
                c = __builtin_amdgcn_mfma_f32_16x16x32_bf16(af[0][i], bfr[0][j], c, 0, 0, 0);
                c = __builtin_amdgcn_mfma_f32_16x16x32_bf16(af[0][i], bfr[1][j], c, 0, 0, 0);
                c = __builtin_amdgcn_mfma_f32_16x16x32_bf16(af[1][i], bfr[0][j], c, 0, 0, 0);
                acc[i][j] = c;
            }
        __syncthreads();
    }

    // epilogue: C/D layout col=lane&15, row=(lane>>4)*4+reg
    const int r0 = (lane >> 4) * 4;
    const int cc = lane & 15;
    if (mode == 0) {
        float* C = Cf + (size_t)k * cBatch;
        const float* bb = bias + (size_t)k * biasBatch;
#pragma unroll
        for (int i = 0; i < 4; i++) {
            int rowb = m0 + wm + i * 16 + r0;
#pragma unroll
            for (int j = 0; j < 4; j++) {
                int col = n0 + wn + j * 16 + cc;
                if (col < Nout) {
                    float b = bb[col];
#pragma unroll
                    for (int r = 0; r < 4; r++)
                        C[(size_t)(rowb + r) * ldc + col] = acc[i][j][r] + b;
                }
            }
        }
    } else {
        short* h0 = H0 + (size_t)k * hBatch;
        short* h1 = H1 + (size_t)k * hBatch;
        const float* bb = bias + (size_t)k * biasBatch;
#pragma unroll
        for (int i = 0; i < 4; i++) {
            int rowb = m0 + wm + i * 16 + r0;
#pragma unroll
            for (int j = 0; j < 4; j++) {
                int col = n0 + wn + j * 16 + cc;
                float b = bb[col];
#pragma unroll
                for (int r = 0; r < 4; r++) {
                    float v = fmaxf(acc[i][j][r] + b, 0.f);
                    short s0, s1; split2(v, s0, s1);
                    size_t o = (size_t)(rowb + r) * 512 + col;
                    h0[o] = s0; h1[o] = s1;
                }
            }
        }
    }
}

// ---------------- per-sample softmax + greedy expert selection + combine ----------------
__global__ __launch_bounds__(256) void gate_combine(
    const float* __restrict__ L,      // [K][Bc][C]
    const int* __restrict__ n_exp,
    float* __restrict__ out_logits,   // [Bc][C] (offset)
    float* __restrict__ out_gates,    // [Bc][K] (offset)
    int Bc)
{
    const int b = blockIdx.x;
    const int tid = threadIdx.x;
    const int lane = tid & 63;
    const int wv = tid >> 6;

    __shared__ float sl[K_EXP][C_DIM];
    __shared__ float wred[4][48];
    __shared__ float m_s[K_EXP];
    __shared__ float zd_s[44];        // [0..7]=Z_k, [8..43]=36 pair dots
    __shared__ float S_s[K_EXP][K_EXP];
    __shared__ float conf_s[K_EXP];
    __shared__ float gates_s[K_EXP];

    const size_t kc_stride = (size_t)Bc * C_DIM;

    // Phase 1: load logits -> LDS, per-expert max
    float mx[K_EXP];
#pragma unroll
    for (int k = 0; k < K_EXP; k++) mx[k] = -INFINITY;
    for (int c = tid; c < C_DIM; c += 256) {
#pragma unroll
        for (int k = 0; k < K_EXP; k++) {
            float v = L[(size_t)k * kc_stride + (size_t)b * C_DIM + c];
            sl[k][c] = v;
            mx[k] = fmaxf(mx[k], v);
        }
    }
#pragma unroll
    for (int k = 0; k < K_EXP; k++)
#pragma unroll
        for (int off = 32; off > 0; off >>= 1)
            mx[k] = fmaxf(mx[k], __shfl_xor(mx[k], off, 64));
    if (lane == 0)
#pragma unroll
        for (int k = 0; k < K_EXP; k++) wred[wv][k] = mx[k];
    __syncthreads();
    if (tid < K_EXP) {
        float m = wred[0][tid];
        for (int w = 1; w < 4; w++) m = fmaxf(m, wred[w][tid]);
        m_s[tid] = m;
    }
    __syncthreads();

    // Phase 2 (merged): single exp pass -> Z_k and 36 pairwise dots
    float v44[44];
#pragma unroll
    for (int p = 0; p < 44; p++) v44[p] = 0.f;
    for (int c = tid; c < C_DIM; c += 256) {
        float e[K_EXP];
#pragma unroll
        for (int k = 0; k < K_EXP; k++) {
            e[k] = __expf(sl[k][c] - m_s[k]);
            v44[k] += e[k];
        }
        int idx = 8;
#pragma unroll
        for (int i = 0; i < K_EXP; i++)
#pragma unroll
            for (int j = i; j < K_EXP; j++) {
                v44[idx] = fmaf(e[i], e[j], v44[idx]);
                idx++;
            }
    }
#pragma unroll
    for (int p = 0; p < 44; p++)
#pragma unroll
        for (int off = 32; off > 0; off >>= 1)
            v44[p] += __shfl_xor(v44[p], off, 64);
    if (lane == 0)
#pragma unroll
        for (int p = 0; p < 44; p++) wred[wv][p] = v44[p];
    __syncthreads();
    if (tid < 44) {
        float s = 0.f;
        for (int w = 0; w < 4; w++) s += wred[w][tid];
        zd_s[tid] = s;
    }
    __syncthreads();

    // Phase 3: serial gating (mirrors reference first-occurrence argmax)
    if (tid == 0) {
        float zk[K_EXP];
#pragma unroll
        for (int k = 0; k < K_EXP; k++) zk[k] = zd_s[k];
        int idx = 8;
        for (int i = 0; i < K_EXP; i++)
            for (int j = i; j < K_EXP; j++) {
                S_s[i][j] = zd_s[idx];
                S_s[j][i] = zd_s[idx];
                idx++;
            }
        float nrm[K_EXP];
#pragma unroll
        for (int k = 0; k < K_EXP; k++) {
            conf_s[k] = 1.0f / zk[k];
            nrm[k] = sqrtf(S_s[k][k]) / zk[k];
        }
        for (int i = 0; i < K_EXP; i++)
            for (int j = 0; j < K_EXP; j++)
                S_s[i][j] = (S_s[i][j] / (zk[i] * zk[j])) /
                            ((nrm[i] + EPS_N) * (nrm[j] + EPS_N));

        int i0 = 0; float bcf = conf_s[0];
        for (int k = 1; k < K_EXP; k++)
            if (conf_s[k] > bcf) { bcf = conf_s[k]; i0 = k; }
        unsigned sel = 1u << i0;
        const int n = n_exp[b];

        for (int t = 1; t < K_EXP; t++) {
            float bd = -INFINITY; int bi = 0; int found = 0;
            for (int i = 0; i < K_EXP; i++) {
                if (sel & (1u << i)) continue;
                float ms = -INFINITY;
                for (int j = 0; j < K_EXP; j++)
                    if (sel & (1u << j)) ms = fmaxf(ms, S_s[i][j]);
                float dist = 1.0f - ms;
                if (!found || dist > bd) { bd = dist; bi = i; found = 1; }
            }
            if (t < n) sel |= 1u << bi;
        }

        float cmax = -INFINITY;
        for (int k = 0; k < K_EXP; k++)
            if (sel & (1u << k)) cmax = fmaxf(cmax, conf_s[k]);
        float gsum = 0.f, g[K_EXP];
        for (int k = 0; k < K_EXP; k++) {
            g[k] = (sel & (1u << k)) ? __expf((conf_s[k] - cmax) * TEMP_INV) : 0.f;
            gsum += g[k];
        }
        for (int k = 0; k < K_EXP; k++) {
            float gv = g[k] / gsum;
            gates_s[k] = gv;
            out_gates[(size_t)b * K_EXP + k] = gv;
        }
    }
    __syncthreads();

    // Phase 4: gated combine from LDS
    for (int c = tid; c < C_DIM; c += 256) {
        float o = 0.f;
#pragma unroll
        for (int k = 0; k < K_EXP; k++)
            o = fmaf(gates_s[k], sl[k][c], o);
        out_logits[(size_t)b * C_DIM + c] = o;
    }
}

// ---------------- launch ----------------
extern "C" void kernel_launch(void* const* d_in, const int* in_sizes, int n_in,
                              void* d_out, int out_size, void* d_ws, size_t ws_size,
                              hipStream_t stream) {
    const float* z     = (const float*)d_in[0];
    const int*   n_exp = (const int*)d_in[1];
    const float* W1    = (const float*)d_in[2];
    const float* b1    = (const float*)d_in[3];
    const float* W2    = (const float*)d_in[4];
    const float* b2    = (const float*)d_in[5];
    float* out_logits = (float*)d_out;
    float* out_gates  = (float*)d_out + (size_t)B_SZ * C_DIM;

    const size_t zP   = (size_t)B_SZ * D_DIM * 2;
    const size_t w1P  = (size_t)K_EXP * D_DIM * D_DIM * 2;
    const size_t w2P  = (size_t)K_EXP * C_PAD * D_DIM * 2;
    const size_t fixedBytes = 2 * (zP + w1P + w2P);   // ~42 MB

    // per chunk: Bc*(2 h planes: 2*8*512*2  +  fp32 logits: 8*1000*4) = Bc*48384
    int nch = 1;
    while (nch < 32 && fixedBytes + (size_t)(B_SZ / nch) * 48384 > ws_size) nch *= 2;
    const int Bc = B_SZ / nch;

    char* w = (char*)d_ws;
    short* zp[2];  zp[0]  = (short*)w; zp[1]  = (short*)(w + zP);  w += 2 * zP;
    short* w1t[2]; w1t[0] = (short*)w; w1t[1] = (short*)(w + w1P); w += 2 * w1P;
    short* w2t[2]; w2t[0] = (short*)w; w2t[1] = (short*)(w + w2P); w += 2 * w2P;
    const size_t hP = (size_t)K_EXP * Bc * D_DIM * 2;
    short* hp[2];  hp[0]  = (short*)w; hp[1]  = (short*)(w + hP);  w += 2 * hP;
    float* Lb = (float*)w;

    prep_z <<<dim3((B_SZ * D_DIM) / 256), 256, 0, stream>>>(z, zp[0], zp[1]);
    prep_w1<<<dim3((K_EXP * D_DIM * D_DIM) / 256), 256, 0, stream>>>(W1, w1t[0], w1t[1]);
    prep_w2<<<dim3((K_EXP * C_PAD * D_DIM) / 256), 256, 0, stream>>>(W2, w2t[0], w2t[1]);

    for (int ch = 0; ch < nch; ch++) {
        const int off = ch * Bc;
        const long long zoff = (long long)off * D_DIM;

        dim3 g1(D_DIM / 128, Bc / 128, K_EXP);
        gemm_split<<<g1, 256, 0, stream>>>(
            zp[0] + zoff, zp[1] + zoff, 0LL,
            w1t[0], w1t[1], (long long)D_DIM * D_DIM,
            b1, D_DIM,
            nullptr, 0LL, 0, D_DIM,
            hp[0], hp[1], (long long)Bc * D_DIM, 1);

        dim3 g2(C_PAD / 128, Bc / 128, K_EXP);
        gemm_split<<<g2, 256, 0, stream>>>(
            hp[0], hp[1], (long long)Bc * D_DIM,
            w2t[0], w2t[1], (long long)C_PAD * D_DIM,
            b2, C_DIM,
            Lb, (long long)Bc * C_DIM, C_DIM, C_DIM,
            nullptr, nullptr, 0LL, 0);

        gate_combine<<<dim3(Bc), 256, 0, stream>>>(
            Lb, n_exp + off,
            out_logits + (size_t)off * C_DIM,
            out_gates + (size_t)off * K_EXP,
            Bc);
    }
}

// Round 4
// 643.360 us; speedup vs baseline: 2.4224x; 1.0785x over previous
//
#include <hip/hip_runtime.h>
#include <math.h>

#define B_SZ 8192
#define D_DIM 512
#define C_DIM 1000
#define C_PAD 1024
#define K_EXP 8
#define TEMP_INV 5.0f
#define EPS_N 1e-8f

typedef __attribute__((ext_vector_type(8))) short frag_ab;
typedef __attribute__((ext_vector_type(4))) float frag_cd;

__device__ __forceinline__ short f2bf(float f) {
    unsigned u = __builtin_bit_cast(unsigned, f);
    unsigned r = (u + 0x7fffu + ((u >> 16) & 1u)) >> 16;
    return (short)r;
}
__device__ __forceinline__ float bf2f(short s) {
    unsigned u = ((unsigned)(unsigned short)s) << 16;
    return __builtin_bit_cast(float, u);
}
// 2-plane split: v ~= s0 + s1, |residual| ~ 2^-18 |v|
__device__ __forceinline__ void split2(float v, short& s0, short& s1) {
    s0 = f2bf(v);
    s1 = f2bf(v - bf2f(s0));
}

// async global->LDS, 16B per lane (LDS dest wave-contiguous: base + lane*16)
__device__ __forceinline__ void gl_lds16(const short* g, short* l) {
    __builtin_amdgcn_global_load_lds(
        (const __attribute__((address_space(1))) unsigned int*)(const void*)g,
        (__attribute__((address_space(3))) unsigned int*)(void*)l,
        16, 0, 0);
}

// ---------------- one-time prep: transpose + 2-way bf16 split ----------------
__global__ __launch_bounds__(256) void prep_z(const float* __restrict__ z,
                                              short* __restrict__ p0, short* __restrict__ p1) {
    int idx = blockIdx.x * 256 + threadIdx.x;   // B_SZ*D_DIM
    float v = z[idx];
    short a, b; split2(v, a, b);
    p0[idx] = a; p1[idx] = b;
}

// W1 [K][d][e] -> W1t [K][e][d]
__global__ __launch_bounds__(256) void prep_w1(const float* __restrict__ W1,
                                               short* __restrict__ p0, short* __restrict__ p1) {
    int idx = blockIdx.x * 256 + threadIdx.x;   // 8*512*512
    int k = idx >> 18;
    int e = (idx >> 9) & 511;
    int d = idx & 511;
    float v = W1[((size_t)k << 18) + (size_t)d * 512 + e];
    short a, b; split2(v, a, b);
    p0[idx] = a; p1[idx] = b;
}

// W2 [K][e][c] -> W2t [K][C_PAD][e], zero rows c>=1000
__global__ __launch_bounds__(256) void prep_w2(const float* __restrict__ W2,
                                               short* __restrict__ p0, short* __restrict__ p1) {
    int idx = blockIdx.x * 256 + threadIdx.x;   // 8*1024*512
    int k = idx >> 19;
    int c = (idx >> 9) & 1023;
    int e = idx & 511;
    float v = (c < C_DIM) ? W2[(size_t)k * (D_DIM * C_DIM) + (size_t)e * C_DIM + c] : 0.f;
    short a, b; split2(v, a, b);
    p0[idx] = a; p1[idx] = b;
}

// ---------------- split-bf16 MFMA GEMM: 128x128x32 tile, 3 products ----------------
// 1-D grid, XCD-affine decode: expert = blockIdx.x % 8 (heuristic XCD match),
// then 4-m-tile × all-n windows so a co-resident window's A+B fits one 4 MB L2.
// A planes: [M][512] bf16 row-major (per-expert stride aBatch; 0 = shared)
// B planes: [N][512] bf16 row-major (weights transposed), N = nt*128
// mode 0: Cf = acc + bias (fp32, guard col<Nout, row stride ldc)
// mode 1: h planes = split2(relu(acc + bias)), row stride 512
__global__ __launch_bounds__(256, 4) void gemm_split(
    const short* __restrict__ A0, const short* __restrict__ A1, long long aBatch,
    const short* __restrict__ B0, const short* __restrict__ B1, long long bBatch,
    const float* __restrict__ bias, int biasBatch,
    float* __restrict__ Cf, long long cBatch, int ldc, int Nout,
    short* __restrict__ H0, short* __restrict__ H1, long long hBatch,
    int mt, int nt, int mode)
{
    const int lin = blockIdx.x;
    const int k = lin & 7;                  // expert ↔ XCD affinity
    const int rem = lin >> 3;
    const int gm = (mt >= 4) ? 4 : mt;      // m-window height
    const int win = rem / (gm * nt);
    const int local = rem % (gm * nt);
    const int m0 = (win * gm + local / nt) * 128;
    const int n0 = (local % nt) * 128;

    const int tid = threadIdx.x;
    const int lane = tid & 63;
    const int wv = tid >> 6;
    const int wm = (wv & 1) * 64;
    const int wn = (wv >> 1) * 64;

    __shared__ short lds[16384];    // A0,A1: 2*4096 shorts; B0,B1: 2*4096 (32 KB)

    const short* gA0 = A0 + (size_t)k * aBatch + (size_t)m0 * 512;
    const short* gA1 = A1 + (size_t)k * aBatch + (size_t)m0 * 512;
    const short* gB0 = B0 + (size_t)k * bBatch + (size_t)n0 * 512;
    const short* gB1 = B1 + (size_t)k * bBatch + (size_t)n0 * 512;
    short* ldsA = lds;
    short* ldsB = lds + 8192;

    frag_cd acc[4][4];
#pragma unroll
    for (int i = 0; i < 4; i++)
#pragma unroll
        for (int j = 0; j < 4; j++)
            acc[i][j] = (frag_cd){0.f, 0.f, 0.f, 0.f};

    const int srow = tid >> 2;      // 0..63
    const int sch  = (tid & 3) * 8; // 16B chunk offset in elements

    for (int k0 = 0; k0 < 512; k0 += 32) {
        const short* ga[2] = {gA0, gA1};
        const short* gb[2] = {gB0, gB1};
#pragma unroll
        for (int p = 0; p < 2; p++) {
#pragma unroll
            for (int hh = 0; hh < 2; hh++) {
                int row = hh * 64 + srow;
                gl_lds16(ga[p] + (size_t)row * 512 + k0 + sch,
                         ldsA + p * 4096 + row * 32 + sch);
                gl_lds16(gb[p] + (size_t)row * 512 + k0 + sch,
                         ldsB + p * 4096 + row * 32 + sch);
            }
        }
        __syncthreads();

        // fragments: A[m=lane&15][k=(lane>>4)*8+j]
        frag_ab af[2][4], bfr[2][4];
#pragma unroll
        for (int p = 0; p < 2; p++)
#pragma unroll
            for (int t = 0; t < 4; t++) {
                af[p][t]  = *(const frag_ab*)(ldsA + p * 4096 + (wm + t * 16 + (lane & 15)) * 32 + (lane >> 4) * 8);
                bfr[p][t] = *(const frag_ab*)(ldsB + p * 4096 + (wn + t * 16 + (lane & 15)) * 32 + (lane >> 4) * 8);
            }

#pragma unroll
        for (int i = 0; i < 4; i++)
#pragma unroll
            for (int j = 0; j < 4; j++) {
                frag_cd c = acc[i][j];
                c = __builtin_amdgcn_mfma_f32_16x16x32_bf16(af[0][i], bfr[0][j], c, 0, 0, 0);
                c = __builtin_amdgcn_mfma_f32_16x16x32_bf16(af[0][i], bfr[1][j], c, 0, 0, 0);
                c = __builtin_amdgcn_mfma_f32_16x16x32_bf16(af[1][i], bfr[0][j], c, 0, 0, 0);
                acc[i][j] = c;
            }
        __syncthreads();
    }

    // epilogue: C/D layout col=lane&15, row=(lane>>4)*4+reg
    const int r0 = (lane >> 4) * 4;
    const int cc = lane & 15;
    if (mode == 0) {
        float* C = Cf + (size_t)k * cBatch;
        const float* bb = bias + (size_t)k * biasBatch;
#pragma unroll
        for (int i = 0; i < 4; i++) {
            int rowb = m0 + wm + i * 16 + r0;
#pragma unroll
            for (int j = 0; j < 4; j++) {
                int col = n0 + wn + j * 16 + cc;
                if (col < Nout) {
                    float b = bb[col];
#pragma unroll
                    for (int r = 0; r < 4; r++)
                        C[(size_t)(rowb + r) * ldc + col] = acc[i][j][r] + b;
                }
            }
        }
    } else {
        short* h0 = H0 + (size_t)k * hBatch;
        short* h1 = H1 + (size_t)k * hBatch;
        const float* bb = bias + (size_t)k * biasBatch;
#pragma unroll
        for (int i = 0; i < 4; i++) {
            int rowb = m0 + wm + i * 16 + r0;
#pragma unroll
            for (int j = 0; j < 4; j++) {
                int col = n0 + wn + j * 16 + cc;
                float b = bb[col];
#pragma unroll
                for (int r = 0; r < 4; r++) {
                    float v = fmaxf(acc[i][j][r] + b, 0.f);
                    short s0, s1; split2(v, s0, s1);
                    size_t o = (size_t)(rowb + r) * 512 + col;
                    h0[o] = s0; h1[o] = s1;
                }
            }
        }
    }
}

// ---------------- per-sample softmax + greedy expert selection + combine ----------------
__global__ __launch_bounds__(256) void gate_combine(
    const float* __restrict__ L,      // [K][Bc][C]
    const int* __restrict__ n_exp,
    float* __restrict__ out_logits,   // [Bc][C] (offset)
    float* __restrict__ out_gates,    // [Bc][K] (offset)
    int Bc)
{
    const int b = blockIdx.x;
    const int tid = threadIdx.x;
    const int lane = tid & 63;
    const int wv = tid >> 6;

    __shared__ float sl[K_EXP][C_DIM];
    __shared__ float wred[4][48];
    __shared__ float m_s[K_EXP];
    __shared__ float zd_s[44];        // [0..7]=Z_k, [8..43]=36 pair dots
    __shared__ float S_s[K_EXP][K_EXP];
    __shared__ float conf_s[K_EXP];
    __shared__ float gates_s[K_EXP];

    const size_t kc_stride = (size_t)Bc * C_DIM;

    float mx[K_EXP];
#pragma unroll
    for (int k = 0; k < K_EXP; k++) mx[k] = -INFINITY;
    for (int c = tid; c < C_DIM; c += 256) {
#pragma unroll
        for (int k = 0; k < K_EXP; k++) {
            float v = L[(size_t)k * kc_stride + (size_t)b * C_DIM + c];
            sl[k][c] = v;
            mx[k] = fmaxf(mx[k], v);
        }
    }
#pragma unroll
    for (int k = 0; k < K_EXP; k++)
#pragma unroll
        for (int off = 32; off > 0; off >>= 1)
            mx[k] = fmaxf(mx[k], __shfl_xor(mx[k], off, 64));
    if (lane == 0)
#pragma unroll
        for (int k = 0; k < K_EXP; k++) wred[wv][k] = mx[k];
    __syncthreads();
    if (tid < K_EXP) {
        float m = wred[0][tid];
        for (int w = 1; w < 4; w++) m = fmaxf(m, wred[w][tid]);
        m_s[tid] = m;
    }
    __syncthreads();

    float v44[44];
#pragma unroll
    for (int p = 0; p < 44; p++) v44[p] = 0.f;
    for (int c = tid; c < C_DIM; c += 256) {
        float e[K_EXP];
#pragma unroll
        for (int k = 0; k < K_EXP; k++) {
            e[k] = __expf(sl[k][c] - m_s[k]);
            v44[k] += e[k];
        }
        int idx = 8;
#pragma unroll
        for (int i = 0; i < K_EXP; i++)
#pragma unroll
            for (int j = i; j < K_EXP; j++) {
                v44[idx] = fmaf(e[i], e[j], v44[idx]);
                idx++;
            }
    }
#pragma unroll
    for (int p = 0; p < 44; p++)
#pragma unroll
        for (int off = 32; off > 0; off >>= 1)
            v44[p] += __shfl_xor(v44[p], off, 64);
    if (lane == 0)
#pragma unroll
        for (int p = 0; p < 44; p++) wred[wv][p] = v44[p];
    __syncthreads();
    if (tid < 44) {
        float s = 0.f;
        for (int w = 0; w < 4; w++) s += wred[w][tid];
        zd_s[tid] = s;
    }
    __syncthreads();

    if (tid == 0) {
        float zk[K_EXP];
#pragma unroll
        for (int k = 0; k < K_EXP; k++) zk[k] = zd_s[k];
        int idx = 8;
        for (int i = 0; i < K_EXP; i++)
            for (int j = i; j < K_EXP; j++) {
                S_s[i][j] = zd_s[idx];
                S_s[j][i] = zd_s[idx];
                idx++;
            }
        float nrm[K_EXP];
#pragma unroll
        for (int k = 0; k < K_EXP; k++) {
            conf_s[k] = 1.0f / zk[k];
            nrm[k] = sqrtf(S_s[k][k]) / zk[k];
        }
        for (int i = 0; i < K_EXP; i++)
            for (int j = 0; j < K_EXP; j++)
                S_s[i][j] = (S_s[i][j] / (zk[i] * zk[j])) /
                            ((nrm[i] + EPS_N) * (nrm[j] + EPS_N));

        int i0 = 0; float bcf = conf_s[0];
        for (int k = 1; k < K_EXP; k++)
            if (conf_s[k] > bcf) { bcf = conf_s[k]; i0 = k; }
        unsigned sel = 1u << i0;
        const int n = n_exp[b];

        for (int t = 1; t < K_EXP; t++) {
            float bd = -INFINITY; int bi = 0; int found = 0;
            for (int i = 0; i < K_EXP; i++) {
                if (sel & (1u << i)) continue;
                float ms = -INFINITY;
                for (int j = 0; j < K_EXP; j++)
                    if (sel & (1u << j)) ms = fmaxf(ms, S_s[i][j]);
                float dist = 1.0f - ms;
                if (!found || dist > bd) { bd = dist; bi = i; found = 1; }
            }
            if (t < n) sel |= 1u << bi;
        }

        float cmax = -INFINITY;
        for (int k = 0; k < K_EXP; k++)
            if (sel & (1u << k)) cmax = fmaxf(cmax, conf_s[k]);
        float gsum = 0.f, g[K_EXP];
        for (int k = 0; k < K_EXP; k++) {
            g[k] = (sel & (1u << k)) ? __expf((conf_s[k] - cmax) * TEMP_INV) : 0.f;
            gsum += g[k];
        }
        for (int k = 0; k < K_EXP; k++) {
            float gv = g[k] / gsum;
            gates_s[k] = gv;
            out_gates[(size_t)b * K_EXP + k] = gv;
        }
    }
    __syncthreads();

    for (int c = tid; c < C_DIM; c += 256) {
        float o = 0.f;
#pragma unroll
        for (int k = 0; k < K_EXP; k++)
            o = fmaf(gates_s[k], sl[k][c], o);
        out_logits[(size_t)b * C_DIM + c] = o;
    }
}

// ---------------- launch ----------------
extern "C" void kernel_launch(void* const* d_in, const int* in_sizes, int n_in,
                              void* d_out, int out_size, void* d_ws, size_t ws_size,
                              hipStream_t stream) {
    const float* z     = (const float*)d_in[0];
    const int*   n_exp = (const int*)d_in[1];
    const float* W1    = (const float*)d_in[2];
    const float* b1    = (const float*)d_in[3];
    const float* W2    = (const float*)d_in[4];
    const float* b2    = (const float*)d_in[5];
    float* out_logits = (float*)d_out;
    float* out_gates  = (float*)d_out + (size_t)B_SZ * C_DIM;

    const size_t zP   = (size_t)B_SZ * D_DIM * 2;
    const size_t w1P  = (size_t)K_EXP * D_DIM * D_DIM * 2;
    const size_t w2P  = (size_t)K_EXP * C_PAD * D_DIM * 2;
    const size_t fixedBytes = 2 * (zP + w1P + w2P);   // ~42 MB

    // per chunk: Bc*(2 h planes: 2*8*512*2  +  fp32 logits: 8*1000*4) = Bc*48384
    int nch = 1;
    while (nch < 32 && fixedBytes + (size_t)(B_SZ / nch) * 48384 > ws_size) nch *= 2;
    const int Bc = B_SZ / nch;

    char* w = (char*)d_ws;
    short* zp[2];  zp[0]  = (short*)w; zp[1]  = (short*)(w + zP);  w += 2 * zP;
    short* w1t[2]; w1t[0] = (short*)w; w1t[1] = (short*)(w + w1P); w += 2 * w1P;
    short* w2t[2]; w2t[0] = (short*)w; w2t[1] = (short*)(w + w2P); w += 2 * w2P;
    const size_t hP = (size_t)K_EXP * Bc * D_DIM * 2;
    short* hp[2];  hp[0]  = (short*)w; hp[1]  = (short*)(w + hP);  w += 2 * hP;
    float* Lb = (float*)w;

    prep_z <<<dim3((B_SZ * D_DIM) / 256), 256, 0, stream>>>(z, zp[0], zp[1]);
    prep_w1<<<dim3((K_EXP * D_DIM * D_DIM) / 256), 256, 0, stream>>>(W1, w1t[0], w1t[1]);
    prep_w2<<<dim3((K_EXP * C_PAD * D_DIM) / 256), 256, 0, stream>>>(W2, w2t[0], w2t[1]);

    const int mt = Bc / 128;

    for (int ch = 0; ch < nch; ch++) {
        const int off = ch * Bc;
        const long long zoff = (long long)off * D_DIM;

        // GEMM1: nt = 512/128 = 4
        gemm_split<<<dim3(8 * mt * 4), 256, 0, stream>>>(
            zp[0] + zoff, zp[1] + zoff, 0LL,
            w1t[0], w1t[1], (long long)D_DIM * D_DIM,
            b1, D_DIM,
            nullptr, 0LL, 0, D_DIM,
            hp[0], hp[1], (long long)Bc * D_DIM,
            mt, 4, 1);

        // GEMM2: nt = 1024/128 = 8
        gemm_split<<<dim3(8 * mt * 8), 256, 0, stream>>>(
            hp[0], hp[1], (long long)Bc * D_DIM,
            w2t[0], w2t[1], (long long)C_PAD * D_DIM,
            b2, C_DIM,
            Lb, (long long)Bc * C_DIM, C_DIM, C_DIM,
            nullptr, nullptr, 0LL,
            mt, 8, 0);

        gate_combine<<<dim3(Bc), 256, 0, stream>>>(
            Lb, n_exp + off,
            out_logits + (size_t)off * C_DIM,
            out_gates + (size_t)off * K_EXP,
            Bc);
    }
}

// Round 5
// 538.103 us; speedup vs baseline: 2.8963x; 1.1956x over previous
//
#include <hip/hip_runtime.h>
#include <math.h>

#define B_SZ 8192
#define D_DIM 512
#define C_DIM 1000
#define C_PAD 1024
#define K_EXP 8
#define TEMP_INV 5.0f
#define EPS_N 1e-8f

typedef __attribute__((ext_vector_type(8))) short frag_ab;
typedef __attribute__((ext_vector_type(4))) float frag_cd;

__device__ __forceinline__ short f2bf(float f) {
    unsigned u = __builtin_bit_cast(unsigned, f);
    unsigned r = (u + 0x7fffu + ((u >> 16) & 1u)) >> 16;
    return (short)r;
}
__device__ __forceinline__ float bf2f(short s) {
    unsigned u = ((unsigned)(unsigned short)s) << 16;
    return __builtin_bit_cast(float, u);
}
// 2-plane split: v ~= s0 + s1, |residual| ~ 2^-18 |v|
__device__ __forceinline__ void split2(float v, short& s0, short& s1) {
    s0 = f2bf(v);
    s1 = f2bf(v - bf2f(s0));
}

// async global->LDS, 16B per lane (LDS dest wave-contiguous: base + lane*16)
__device__ __forceinline__ void gl_lds16(const short* g, short* l) {
    __builtin_amdgcn_global_load_lds(
        (const __attribute__((address_space(1))) unsigned int*)(const void*)g,
        (__attribute__((address_space(3))) unsigned int*)(void*)l,
        16, 0, 0);
}

// ---------------- one-time prep: transpose + 2-way bf16 split ----------------
__global__ __launch_bounds__(256) void prep_z(const float* __restrict__ z,
                                              short* __restrict__ p0, short* __restrict__ p1) {
    int idx = blockIdx.x * 256 + threadIdx.x;
    float v = z[idx];
    short a, b; split2(v, a, b);
    p0[idx] = a; p1[idx] = b;
}

// W1 [K][d][e] -> W1t [K][e][d]
__global__ __launch_bounds__(256) void prep_w1(const float* __restrict__ W1,
                                               short* __restrict__ p0, short* __restrict__ p1) {
    int idx = blockIdx.x * 256 + threadIdx.x;
    int k = idx >> 18;
    int e = (idx >> 9) & 511;
    int d = idx & 511;
    float v = W1[((size_t)k << 18) + (size_t)d * 512 + e];
    short a, b; split2(v, a, b);
    p0[idx] = a; p1[idx] = b;
}

// W2 [K][e][c] -> W2t [K][C_PAD][e], zero rows c>=1000
__global__ __launch_bounds__(256) void prep_w2(const float* __restrict__ W2,
                                               short* __restrict__ p0, short* __restrict__ p1) {
    int idx = blockIdx.x * 256 + threadIdx.x;
    int k = idx >> 19;
    int c = (idx >> 9) & 1023;
    int e = idx & 511;
    float v = (c < C_DIM) ? W2[(size_t)k * (D_DIM * C_DIM) + (size_t)e * C_DIM + c] : 0.f;
    short a, b; split2(v, a, b);
    p0[idx] = a; p1[idx] = b;
}

// ---------------- split-bf16 MFMA GEMM: 128x128x32 tile, 3 products ----------------
__global__ __launch_bounds__(256, 4) void gemm_split(
    const short* __restrict__ A0, const short* __restrict__ A1, long long aBatch,
    const short* __restrict__ B0, const short* __restrict__ B1, long long bBatch,
    const float* __restrict__ bias, int biasBatch,
    float* __restrict__ Cf, long long cBatch, int ldc, int Nout,
    short* __restrict__ H0, short* __restrict__ H1, long long hBatch,
    int mt, int nt, int mode)
{
    const int lin = blockIdx.x;
    const int k = lin & 7;                  // expert ↔ XCD affinity
    const int rem = lin >> 3;
    const int gm = (mt >= 4) ? 4 : mt;      // m-window height
    const int win = rem / (gm * nt);
    const int local = rem % (gm * nt);
    const int m0 = (win * gm + local / nt) * 128;
    const int n0 = (local % nt) * 128;

    const int tid = threadIdx.x;
    const int lane = tid & 63;
    const int wv = tid >> 6;
    const int wm = (wv & 1) * 64;
    const int wn = (wv >> 1) * 64;

    __shared__ short lds[16384];

    const short* gA0 = A0 + (size_t)k * aBatch + (size_t)m0 * 512;
    const short* gA1 = A1 + (size_t)k * aBatch + (size_t)m0 * 512;
    const short* gB0 = B0 + (size_t)k * bBatch + (size_t)n0 * 512;
    const short* gB1 = B1 + (size_t)k * bBatch + (size_t)n0 * 512;
    short* ldsA = lds;
    short* ldsB = lds + 8192;

    frag_cd acc[4][4];
#pragma unroll
    for (int i = 0; i < 4; i++)
#pragma unroll
        for (int j = 0; j < 4; j++)
            acc[i][j] = (frag_cd){0.f, 0.f, 0.f, 0.f};

    const int srow = tid >> 2;
    const int sch  = (tid & 3) * 8;

    for (int k0 = 0; k0 < 512; k0 += 32) {
        const short* ga[2] = {gA0, gA1};
        const short* gb[2] = {gB0, gB1};
#pragma unroll
        for (int p = 0; p < 2; p++) {
#pragma unroll
            for (int hh = 0; hh < 2; hh++) {
                int row = hh * 64 + srow;
                gl_lds16(ga[p] + (size_t)row * 512 + k0 + sch,
                         ldsA + p * 4096 + row * 32 + sch);
                gl_lds16(gb[p] + (size_t)row * 512 + k0 + sch,
                         ldsB + p * 4096 + row * 32 + sch);
            }
        }
        __syncthreads();

        frag_ab af[2][4], bfr[2][4];
#pragma unroll
        for (int p = 0; p < 2; p++)
#pragma unroll
            for (int t = 0; t < 4; t++) {
                af[p][t]  = *(const frag_ab*)(ldsA + p * 4096 + (wm + t * 16 + (lane & 15)) * 32 + (lane >> 4) * 8);
                bfr[p][t] = *(const frag_ab*)(ldsB + p * 4096 + (wn + t * 16 + (lane & 15)) * 32 + (lane >> 4) * 8);
            }

#pragma unroll
        for (int i = 0; i < 4; i++)
#pragma unroll
            for (int j = 0; j < 4; j++) {
                frag_cd c = acc[i][j];
                c = __builtin_amdgcn_mfma_f32_16x16x32_bf16(af[0][i], bfr[0][j], c, 0, 0, 0);
                c = __builtin_amdgcn_mfma_f32_16x16x32_bf16(af[0][i], bfr[1][j], c, 0, 0, 0);
                c = __builtin_amdgcn_mfma_f32_16x16x32_bf16(af[1][i], bfr[0][j], c, 0, 0, 0);
                acc[i][j] = c;
            }
        __syncthreads();
    }

    const int r0 = (lane >> 4) * 4;
    const int cc = lane & 15;
    if (mode == 0) {
        float* C = Cf + (size_t)k * cBatch;
        const float* bb = bias + (size_t)k * biasBatch;
#pragma unroll
        for (int i = 0; i < 4; i++) {
            int rowb = m0 + wm + i * 16 + r0;
#pragma unroll
            for (int j = 0; j < 4; j++) {
                int col = n0 + wn + j * 16 + cc;
                if (col < Nout) {
                    float b = bb[col];
#pragma unroll
                    for (int r = 0; r < 4; r++)
                        C[(size_t)(rowb + r) * ldc + col] = acc[i][j][r] + b;
                }
            }
        }
    } else {
        short* h0 = H0 + (size_t)k * hBatch;
        short* h1 = H1 + (size_t)k * hBatch;
        const float* bb = bias + (size_t)k * biasBatch;
#pragma unroll
        for (int i = 0; i < 4; i++) {
            int rowb = m0 + wm + i * 16 + r0;
#pragma unroll
            for (int j = 0; j < 4; j++) {
                int col = n0 + wn + j * 16 + cc;
                float b = bb[col];
#pragma unroll
                for (int r = 0; r < 4; r++) {
                    float v = fmaxf(acc[i][j][r] + b, 0.f);
                    short s0, s1; split2(v, s0, s1);
                    size_t o = (size_t)(rowb + r) * 512 + col;
                    h0[o] = s0; h1[o] = s1;
                }
            }
        }
    }
}

// ---------------- gate + combine: ONE WAVE PER SAMPLE, wave-synchronous ----------------
// L: [K][Bc][C]. Block = 256 threads = 4 independent sample-waves. No __syncthreads.
__global__ __launch_bounds__(256) void gate_combine(
    const float* __restrict__ L,
    const int* __restrict__ n_exp,
    float* __restrict__ out_logits,   // [Bc][C] (offset)
    float* __restrict__ out_gates,    // [Bc][K] (offset)
    int Bc)
{
    const int wv = threadIdx.x >> 6;
    const int lane = threadIdx.x & 63;
    const int b = blockIdx.x * 4 + wv;
    const size_t kcs = (size_t)Bc * C_DIM;
    const float* Lb = L + (size_t)b * C_DIM;

    __shared__ float Sm[4][64];   // full 8x8 dot matrix per wave
    __shared__ float Zm[4][8];

    // single fused pass: per-expert max, Z (no shift: |logit| ~ O(5)), 36 pair dots
    float mx[K_EXP], Zs[K_EXP], dd[36];
#pragma unroll
    for (int k = 0; k < K_EXP; k++) { mx[k] = -INFINITY; Zs[k] = 0.f; }
#pragma unroll
    for (int p = 0; p < 36; p++) dd[p] = 0.f;

    for (int c = lane; c < C_DIM; c += 64) {
        float e[K_EXP];
#pragma unroll
        for (int k = 0; k < K_EXP; k++) {
            float l = Lb[(size_t)k * kcs + c];
            mx[k] = fmaxf(mx[k], l);
            e[k] = __expf(l);
            Zs[k] += e[k];
        }
        int idx = 0;
#pragma unroll
        for (int i = 0; i < K_EXP; i++)
#pragma unroll
            for (int j = i; j < K_EXP; j++) {
                dd[idx] = fmaf(e[i], e[j], dd[idx]);
                idx++;
            }
    }

    // one butterfly: every lane ends with all 52 totals
#pragma unroll
    for (int off = 32; off > 0; off >>= 1) {
#pragma unroll
        for (int k = 0; k < K_EXP; k++) {
            mx[k] = fmaxf(mx[k], __shfl_xor(mx[k], off, 64));
            Zs[k] += __shfl_xor(Zs[k], off, 64);
        }
#pragma unroll
        for (int p = 0; p < 36; p++)
            dd[p] += __shfl_xor(dd[p], off, 64);
    }

    // publish S and Z to LDS for lane-indexed access (lane = (i,j))
    if (lane == 0) {
        int idx = 0;
#pragma unroll
        for (int i = 0; i < K_EXP; i++)
#pragma unroll
            for (int j = i; j < K_EXP; j++) {
                Sm[wv][i * 8 + j] = dd[idx];
                Sm[wv][j * 8 + i] = dd[idx];
                idx++;
            }
#pragma unroll
        for (int k = 0; k < K_EXP; k++) Zm[wv][k] = Zs[k];
    }
    // same wave: ds_write -> ds_read ordered by lgkmcnt (compiler-inserted)

    const int ti = lane >> 3, tj = lane & 7;
    const float Zi = Zm[wv][ti], Zj = Zm[wv][tj];
    const float dij = Sm[wv][ti * 8 + tj];
    const float dii = Sm[wv][ti * 8 + ti];
    const float djj = Sm[wv][tj * 8 + tj];
    const float ni = sqrtf(dii) / Zi + EPS_N;
    const float nj = sqrtf(djj) / Zj + EPS_N;
    const float cosij = (dij / (Zi * Zj)) / (ni * nj);

    float conf[K_EXP];
#pragma unroll
    for (int k = 0; k < K_EXP; k++) conf[k] = __expf(mx[k]) / Zs[k];

    // sel0 = first-occurrence argmax(conf) — uniform across lanes
    int i0 = 0; float bcf = conf[0];
#pragma unroll
    for (int k = 1; k < K_EXP; k++)
        if (conf[k] > bcf) { bcf = conf[k]; i0 = k; }
    unsigned sel = 1u << i0;
    const int n = n_exp[b];

    // greedy max-min-cos selection, lane-parallel: lane (i=ti, j=tj)
    for (int t = 1; t < K_EXP; t++) {
        float v = ((sel >> tj) & 1u) ? cosij : -INFINITY;
        v = fmaxf(v, __shfl_xor(v, 1, 64));
        v = fmaxf(v, __shfl_xor(v, 2, 64));
        v = fmaxf(v, __shfl_xor(v, 4, 64));          // max over selected j, per candidate i
        float dist = ((sel >> ti) & 1u) ? -INFINITY : 1.0f - v;
        float bv = dist; int bi = ti;
#pragma unroll
        for (int off = 8; off < 64; off <<= 1) {      // argmax over i, first-occurrence ties
            float ov = __shfl_xor(bv, off, 64);
            int oi = __shfl_xor(bi, off, 64);
            if (ov > bv || (ov == bv && oi < bi)) { bv = ov; bi = oi; }
        }
        if (t < n) sel |= 1u << bi;
    }

    // gates (uniform, all lanes redundantly)
    float cmax = -INFINITY;
#pragma unroll
    for (int k = 0; k < K_EXP; k++)
        if ((sel >> k) & 1u) cmax = fmaxf(cmax, conf[k]);
    float g[K_EXP], gsum = 0.f;
#pragma unroll
    for (int k = 0; k < K_EXP; k++) {
        g[k] = ((sel >> k) & 1u) ? __expf((conf[k] - cmax) * TEMP_INV) : 0.f;
        gsum += g[k];
    }
    const float ginv = 1.0f / gsum;
#pragma unroll
    for (int k = 0; k < K_EXP; k++) g[k] *= ginv;

    if (lane == 0) {
        float4* og = (float4*)(out_gates + (size_t)b * K_EXP);
        og[0] = make_float4(g[0], g[1], g[2], g[3]);
        og[1] = make_float4(g[4], g[5], g[6], g[7]);
    }

    // gated combine (re-read L: L2/L3-resident)
    for (int c = lane; c < C_DIM; c += 64) {
        float o = 0.f;
#pragma unroll
        for (int k = 0; k < K_EXP; k++)
            o = fmaf(g[k], Lb[(size_t)k * kcs + c], o);
        out_logits[(size_t)b * C_DIM + c] = o;
    }
}

// ---------------- launch ----------------
extern "C" void kernel_launch(void* const* d_in, const int* in_sizes, int n_in,
                              void* d_out, int out_size, void* d_ws, size_t ws_size,
                              hipStream_t stream) {
    const float* z     = (const float*)d_in[0];
    const int*   n_exp = (const int*)d_in[1];
    const float* W1    = (const float*)d_in[2];
    const float* b1    = (const float*)d_in[3];
    const float* W2    = (const float*)d_in[4];
    const float* b2    = (const float*)d_in[5];
    float* out_logits = (float*)d_out;
    float* out_gates  = (float*)d_out + (size_t)B_SZ * C_DIM;

    const size_t zP   = (size_t)B_SZ * D_DIM * 2;
    const size_t w1P  = (size_t)K_EXP * D_DIM * D_DIM * 2;
    const size_t w2P  = (size_t)K_EXP * C_PAD * D_DIM * 2;
    const size_t fixedBytes = 2 * (zP + w1P + w2P);   // ~42 MB

    int nch = 1;
    while (nch < 32 && fixedBytes + (size_t)(B_SZ / nch) * 48384 > ws_size) nch *= 2;
    const int Bc = B_SZ / nch;

    char* w = (char*)d_ws;
    short* zp[2];  zp[0]  = (short*)w; zp[1]  = (short*)(w + zP);  w += 2 * zP;
    short* w1t[2]; w1t[0] = (short*)w; w1t[1] = (short*)(w + w1P); w += 2 * w1P;
    short* w2t[2]; w2t[0] = (short*)w; w2t[1] = (short*)(w + w2P); w += 2 * w2P;
    const size_t hP = (size_t)K_EXP * Bc * D_DIM * 2;
    short* hp[2];  hp[0]  = (short*)w; hp[1]  = (short*)(w + hP);  w += 2 * hP;
    float* Lb = (float*)w;

    prep_z <<<dim3((B_SZ * D_DIM) / 256), 256, 0, stream>>>(z, zp[0], zp[1]);
    prep_w1<<<dim3((K_EXP * D_DIM * D_DIM) / 256), 256, 0, stream>>>(W1, w1t[0], w1t[1]);
    prep_w2<<<dim3((K_EXP * C_PAD * D_DIM) / 256), 256, 0, stream>>>(W2, w2t[0], w2t[1]);

    const int mt = Bc / 128;

    for (int ch = 0; ch < nch; ch++) {
        const int off = ch * Bc;
        const long long zoff = (long long)off * D_DIM;

        gemm_split<<<dim3(8 * mt * 4), 256, 0, stream>>>(
            zp[0] + zoff, zp[1] + zoff, 0LL,
            w1t[0], w1t[1], (long long)D_DIM * D_DIM,
            b1, D_DIM,
            nullptr, 0LL, 0, D_DIM,
            hp[0], hp[1], (long long)Bc * D_DIM,
            mt, 4, 1);

        gemm_split<<<dim3(8 * mt * 8), 256, 0, stream>>>(
            hp[0], hp[1], (long long)Bc * D_DIM,
            w2t[0], w2t[1], (long long)C_PAD * D_DIM,
            b2, C_DIM,
            Lb, (long long)Bc * C_DIM, C_DIM, C_DIM,
            nullptr, nullptr, 0LL,
            mt, 8, 0);

        gate_combine<<<dim3(Bc / 4), 256, 0, stream>>>(
            Lb, n_exp + off,
            out_logits + (size_t)off * C_DIM,
            out_gates + (size_t)off * K_EXP,
            Bc);
    }
}

// Round 6
// 516.588 us; speedup vs baseline: 3.0169x; 1.0416x over previous
//
#include <hip/hip_runtime.h>
#include <math.h>

#define B_SZ 8192
#define D_DIM 512
#define C_DIM 1000
#define C_PAD 1024
#define K_EXP 8
#define TEMP_INV 5.0f
#define EPS_N 1e-8f

typedef __attribute__((ext_vector_type(8))) short frag_ab;
typedef __attribute__((ext_vector_type(4))) float frag_cd;

__device__ __forceinline__ short f2bf(float f) {
    unsigned u = __builtin_bit_cast(unsigned, f);
    unsigned r = (u + 0x7fffu + ((u >> 16) & 1u)) >> 16;
    return (short)r;
}
__device__ __forceinline__ float bf2f(short s) {
    unsigned u = ((unsigned)(unsigned short)s) << 16;
    return __builtin_bit_cast(float, u);
}
// 2-plane split: v ~= s0 + s1, |residual| ~ 2^-18 |v|
__device__ __forceinline__ void split2(float v, short& s0, short& s1) {
    s0 = f2bf(v);
    s1 = f2bf(v - bf2f(s0));
}

// async global->LDS, 16B per lane (LDS dest wave-contiguous: base + lane*16)
__device__ __forceinline__ void gl_lds16(const short* g, short* l) {
    __builtin_amdgcn_global_load_lds(
        (const __attribute__((address_space(1))) unsigned int*)(const void*)g,
        (__attribute__((address_space(3))) unsigned int*)(void*)l,
        16, 0, 0);
}

// ---------------- one-time prep: transpose + 2-way bf16 split ----------------
__global__ __launch_bounds__(256) void prep_z(const float* __restrict__ z,
                                              short* __restrict__ p0, short* __restrict__ p1) {
    int idx = blockIdx.x * 256 + threadIdx.x;
    float v = z[idx];
    short a, b; split2(v, a, b);
    p0[idx] = a; p1[idx] = b;
}

// W1 [K][d][e] -> planes [K][e][d], LDS 32x32 tile transpose (coalesced both sides)
__global__ __launch_bounds__(256) void prep_w1t(const float* __restrict__ W1,
                                                short* __restrict__ p0, short* __restrict__ p1) {
    __shared__ float t[32][33];
    const int k = blockIdx.z;
    const int d0 = blockIdx.x * 32;
    const int e0 = blockIdx.y * 32;
    const int tx = threadIdx.x & 31, ty = threadIdx.x >> 5;
    const float* src = W1 + ((size_t)k << 18);
#pragma unroll
    for (int r = 0; r < 4; r++) {
        int d = d0 + ty + 8 * r;
        t[ty + 8 * r][tx] = src[(size_t)d * 512 + e0 + tx];
    }
    __syncthreads();
#pragma unroll
    for (int r = 0; r < 4; r++) {
        int e = e0 + ty + 8 * r;
        int d = d0 + tx;
        float v = t[tx][ty + 8 * r];
        short a, b; split2(v, a, b);
        size_t o = ((size_t)k << 18) + (size_t)e * 512 + d;
        p0[o] = a; p1[o] = b;
    }
}

// W2 [K][e][c] -> planes [K][c_pad][e] (zero rows c>=1000), 32x32 tile transpose
__global__ __launch_bounds__(256) void prep_w2t(const float* __restrict__ W2,
                                                short* __restrict__ p0, short* __restrict__ p1) {
    __shared__ float t[32][33];
    const int k = blockIdx.z;
    const int e0 = blockIdx.x * 32;   // source row (e) block, 16 blocks
    const int c0 = blockIdx.y * 32;   // source col (c) block, 32 blocks
    const int tx = threadIdx.x & 31, ty = threadIdx.x >> 5;
    const float* src = W2 + (size_t)k * (D_DIM * C_DIM);
#pragma unroll
    for (int r = 0; r < 4; r++) {
        int e = e0 + ty + 8 * r;
        int c = c0 + tx;
        t[ty + 8 * r][tx] = (c < C_DIM) ? src[(size_t)e * C_DIM + c] : 0.f;
    }
    __syncthreads();
#pragma unroll
    for (int r = 0; r < 4; r++) {
        int c = c0 + ty + 8 * r;
        int e = e0 + tx;
        float v = t[tx][ty + 8 * r];
        short a, b; split2(v, a, b);
        size_t o = (size_t)k * (C_PAD * D_DIM) + (size_t)c * 512 + e;
        p0[o] = a; p1[o] = b;
    }
}

// ---------------- split-bf16 MFMA GEMM: 128x128x32 tile, 3 products ----------------
// Double-buffered LDS (2x32KB), ONE barrier per K-iter: loads for iter t+1 are
// issued at top of iter t and drained by the barrier at top of iter t+1 — the
// vmcnt(0) drain overlaps the full compute phase instead of stalling.
__global__ __launch_bounds__(256, 2) void gemm_split(
    const short* __restrict__ A0, const short* __restrict__ A1, long long aBatch,
    const short* __restrict__ B0, const short* __restrict__ B1, long long bBatch,
    const float* __restrict__ bias, int biasBatch,
    float* __restrict__ Cf, long long cBatch, int ldc, int Nout,
    short* __restrict__ H0, short* __restrict__ H1, long long hBatch,
    int mt, int nt, int mode)
{
    const int lin = blockIdx.x;
    const int k = lin & 7;                  // expert ↔ XCD affinity
    const int rem = lin >> 3;
    const int gm = (mt >= 4) ? 4 : mt;
    const int win = rem / (gm * nt);
    const int local = rem % (gm * nt);
    const int m0 = (win * gm + local / nt) * 128;
    const int n0 = (local % nt) * 128;

    const int tid = threadIdx.x;
    const int lane = tid & 63;
    const int wv = tid >> 6;
    const int wm = (wv & 1) * 64;
    const int wn = (wv >> 1) * 64;

    __shared__ short lds[32768];   // two 32 KB buffers

    const short* gA0 = A0 + (size_t)k * aBatch + (size_t)m0 * 512;
    const short* gA1 = A1 + (size_t)k * aBatch + (size_t)m0 * 512;
    const short* gB0 = B0 + (size_t)k * bBatch + (size_t)n0 * 512;
    const short* gB1 = B1 + (size_t)k * bBatch + (size_t)n0 * 512;

    frag_cd acc[4][4];
#pragma unroll
    for (int i = 0; i < 4; i++)
#pragma unroll
        for (int j = 0; j < 4; j++)
            acc[i][j] = (frag_cd){0.f, 0.f, 0.f, 0.f};

    const int srow = tid >> 2;
    const int sch  = (tid & 3) * 8;

    auto stage = [&](int k0, short* buf) {
        short* bA = buf;
        short* bB = buf + 8192;
        const short* ga[2] = {gA0, gA1};
        const short* gb[2] = {gB0, gB1};
#pragma unroll
        for (int p = 0; p < 2; p++)
#pragma unroll
            for (int hh = 0; hh < 2; hh++) {
                int row = hh * 64 + srow;
                gl_lds16(ga[p] + (size_t)row * 512 + k0 + sch, bA + p * 4096 + row * 32 + sch);
                gl_lds16(gb[p] + (size_t)row * 512 + k0 + sch, bB + p * 4096 + row * 32 + sch);
            }
    };

    stage(0, lds);

    for (int it = 0; it < 16; it++) {
        short* curb = lds + (it & 1) * 16384;
        short* nxtb = lds + ((it + 1) & 1) * 16384;
        __syncthreads();                       // drains prev-issued loads (overlapped) + WAR sync
        if (it + 1 < 16) stage((it + 1) * 32, nxtb);

        short* ldsA = curb;
        short* ldsB = curb + 8192;
        frag_ab af[2][4], bfr[2][4];
#pragma unroll
        for (int p = 0; p < 2; p++)
#pragma unroll
            for (int t = 0; t < 4; t++) {
                af[p][t]  = *(const frag_ab*)(ldsA + p * 4096 + (wm + t * 16 + (lane & 15)) * 32 + (lane >> 4) * 8);
                bfr[p][t] = *(const frag_ab*)(ldsB + p * 4096 + (wn + t * 16 + (lane & 15)) * 32 + (lane >> 4) * 8);
            }

#pragma unroll
        for (int i = 0; i < 4; i++)
#pragma unroll
            for (int j = 0; j < 4; j++) {
                frag_cd c = acc[i][j];
                c = __builtin_amdgcn_mfma_f32_16x16x32_bf16(af[0][i], bfr[0][j], c, 0, 0, 0);
                c = __builtin_amdgcn_mfma_f32_16x16x32_bf16(af[0][i], bfr[1][j], c, 0, 0, 0);
                c = __builtin_amdgcn_mfma_f32_16x16x32_bf16(af[1][i], bfr[0][j], c, 0, 0, 0);
                acc[i][j] = c;
            }
    }

    // epilogue: C/D layout col=lane&15, row=(lane>>4)*4+reg
    const int r0 = (lane >> 4) * 4;
    const int cc = lane & 15;
    if (mode == 0) {
        float* C = Cf + (size_t)k * cBatch;
        const float* bb = bias + (size_t)k * biasBatch;
#pragma unroll
        for (int i = 0; i < 4; i++) {
            int rowb = m0 + wm + i * 16 + r0;
#pragma unroll
            for (int j = 0; j < 4; j++) {
                int col = n0 + wn + j * 16 + cc;
                if (col < Nout) {
                    float b = bb[col];
#pragma unroll
                    for (int r = 0; r < 4; r++)
                        C[(size_t)(rowb + r) * ldc + col] = acc[i][j][r] + b;
                }
            }
        }
    } else {
        short* h0 = H0 + (size_t)k * hBatch;
        short* h1 = H1 + (size_t)k * hBatch;
        const float* bb = bias + (size_t)k * biasBatch;
#pragma unroll
        for (int i = 0; i < 4; i++) {
            int rowb = m0 + wm + i * 16 + r0;
#pragma unroll
            for (int j = 0; j < 4; j++) {
                int col = n0 + wn + j * 16 + cc;
                float b = bb[col];
#pragma unroll
                for (int r = 0; r < 4; r++) {
                    float v = fmaxf(acc[i][j][r] + b, 0.f);
                    short s0, s1; split2(v, s0, s1);
                    size_t o = (size_t)(rowb + r) * 512 + col;
                    h0[o] = s0; h1[o] = s1;
                }
            }
        }
    }
}

// ---------------- gate + combine: one wave per sample, wave-synchronous ----------------
__global__ __launch_bounds__(256) void gate_combine(
    const float* __restrict__ L,
    const int* __restrict__ n_exp,
    float* __restrict__ out_logits,   // [Bc][C] (offset)
    float* __restrict__ out_gates,    // [Bc][K] (offset)
    int Bc)
{
    const int wv = threadIdx.x >> 6;
    const int lane = threadIdx.x & 63;
    const int b = blockIdx.x * 4 + wv;
    const size_t kcs = (size_t)Bc * C_DIM;
    const float* Lb = L + (size_t)b * C_DIM;

    __shared__ float Sm[4][64];
    __shared__ float Zm[4][8];

    float mx[K_EXP], Zs[K_EXP], dd[36];
#pragma unroll
    for (int k = 0; k < K_EXP; k++) { mx[k] = -INFINITY; Zs[k] = 0.f; }
#pragma unroll
    for (int p = 0; p < 36; p++) dd[p] = 0.f;

    for (int c = lane; c < C_DIM; c += 64) {
        float e[K_EXP];
#pragma unroll
        for (int k = 0; k < K_EXP; k++) {
            float l = Lb[(size_t)k * kcs + c];
            mx[k] = fmaxf(mx[k], l);
            e[k] = __expf(l);
            Zs[k] += e[k];
        }
        int idx = 0;
#pragma unroll
        for (int i = 0; i < K_EXP; i++)
#pragma unroll
            for (int j = i; j < K_EXP; j++) {
                dd[idx] = fmaf(e[i], e[j], dd[idx]);
                idx++;
            }
    }

#pragma unroll
    for (int off = 32; off > 0; off >>= 1) {
#pragma unroll
        for (int k = 0; k < K_EXP; k++) {
            mx[k] = fmaxf(mx[k], __shfl_xor(mx[k], off, 64));
            Zs[k] += __shfl_xor(Zs[k], off, 64);
        }
#pragma unroll
        for (int p = 0; p < 36; p++)
            dd[p] += __shfl_xor(dd[p], off, 64);
    }

    if (lane == 0) {
        int idx = 0;
#pragma unroll
        for (int i = 0; i < K_EXP; i++)
#pragma unroll
            for (int j = i; j < K_EXP; j++) {
                Sm[wv][i * 8 + j] = dd[idx];
                Sm[wv][j * 8 + i] = dd[idx];
                idx++;
            }
#pragma unroll
        for (int k = 0; k < K_EXP; k++) Zm[wv][k] = Zs[k];
    }

    const int ti = lane >> 3, tj = lane & 7;
    const float Zi = Zm[wv][ti], Zj = Zm[wv][tj];
    const float dij = Sm[wv][ti * 8 + tj];
    const float dii = Sm[wv][ti * 8 + ti];
    const float djj = Sm[wv][tj * 8 + tj];
    const float ni = sqrtf(dii) / Zi + EPS_N;
    const float nj = sqrtf(djj) / Zj + EPS_N;
    const float cosij = (dij / (Zi * Zj)) / (ni * nj);

    float conf[K_EXP];
#pragma unroll
    for (int k = 0; k < K_EXP; k++) conf[k] = __expf(mx[k]) / Zs[k];

    int i0 = 0; float bcf = conf[0];
#pragma unroll
    for (int k = 1; k < K_EXP; k++)
        if (conf[k] > bcf) { bcf = conf[k]; i0 = k; }
    unsigned sel = 1u << i0;
    const int n = n_exp[b];

    for (int t = 1; t < K_EXP; t++) {
        float v = ((sel >> tj) & 1u) ? cosij : -INFINITY;
        v = fmaxf(v, __shfl_xor(v, 1, 64));
        v = fmaxf(v, __shfl_xor(v, 2, 64));
        v = fmaxf(v, __shfl_xor(v, 4, 64));
        float dist = ((sel >> ti) & 1u) ? -INFINITY : 1.0f - v;
        float bv = dist; int bi = ti;
#pragma unroll
        for (int off = 8; off < 64; off <<= 1) {
            float ov = __shfl_xor(bv, off, 64);
            int oi = __shfl_xor(bi, off, 64);
            if (ov > bv || (ov == bv && oi < bi)) { bv = ov; bi = oi; }
        }
        if (t < n) sel |= 1u << bi;
    }

    float cmax = -INFINITY;
#pragma unroll
    for (int k = 0; k < K_EXP; k++)
        if ((sel >> k) & 1u) cmax = fmaxf(cmax, conf[k]);
    float g[K_EXP], gsum = 0.f;
#pragma unroll
    for (int k = 0; k < K_EXP; k++) {
        g[k] = ((sel >> k) & 1u) ? __expf((conf[k] - cmax) * TEMP_INV) : 0.f;
        gsum += g[k];
    }
    const float ginv = 1.0f / gsum;
#pragma unroll
    for (int k = 0; k < K_EXP; k++) g[k] *= ginv;

    if (lane == 0) {
        float4* og = (float4*)(out_gates + (size_t)b * K_EXP);
        og[0] = make_float4(g[0], g[1], g[2], g[3]);
        og[1] = make_float4(g[4], g[5], g[6], g[7]);
    }

    for (int c = lane; c < C_DIM; c += 64) {
        float o = 0.f;
#pragma unroll
        for (int k = 0; k < K_EXP; k++)
            o = fmaf(g[k], Lb[(size_t)k * kcs + c], o);
        out_logits[(size_t)b * C_DIM + c] = o;
    }
}

// ---------------- launch ----------------
extern "C" void kernel_launch(void* const* d_in, const int* in_sizes, int n_in,
                              void* d_out, int out_size, void* d_ws, size_t ws_size,
                              hipStream_t stream) {
    const float* z     = (const float*)d_in[0];
    const int*   n_exp = (const int*)d_in[1];
    const float* W1    = (const float*)d_in[2];
    const float* b1    = (const float*)d_in[3];
    const float* W2    = (const float*)d_in[4];
    const float* b2    = (const float*)d_in[5];
    float* out_logits = (float*)d_out;
    float* out_gates  = (float*)d_out + (size_t)B_SZ * C_DIM;

    const size_t zP   = (size_t)B_SZ * D_DIM * 2;
    const size_t w1P  = (size_t)K_EXP * D_DIM * D_DIM * 2;
    const size_t w2P  = (size_t)K_EXP * C_PAD * D_DIM * 2;
    const size_t fixedBytes = 2 * (zP + w1P + w2P);   // ~42 MB

    int nch = 1;
    while (nch < 32 && fixedBytes + (size_t)(B_SZ / nch) * 48384 > ws_size) nch *= 2;
    const int Bc = B_SZ / nch;

    char* w = (char*)d_ws;
    short* zp[2];  zp[0]  = (short*)w; zp[1]  = (short*)(w + zP);  w += 2 * zP;
    short* w1t[2]; w1t[0] = (short*)w; w1t[1] = (short*)(w + w1P); w += 2 * w1P;
    short* w2t[2]; w2t[0] = (short*)w; w2t[1] = (short*)(w + w2P); w += 2 * w2P;
    const size_t hP = (size_t)K_EXP * Bc * D_DIM * 2;
    short* hp[2];  hp[0]  = (short*)w; hp[1]  = (short*)(w + hP);  w += 2 * hP;
    float* Lb = (float*)w;

    prep_z <<<dim3((B_SZ * D_DIM) / 256), 256, 0, stream>>>(z, zp[0], zp[1]);
    prep_w1t<<<dim3(16, 16, K_EXP), 256, 0, stream>>>(W1, w1t[0], w1t[1]);
    prep_w2t<<<dim3(16, 32, K_EXP), 256, 0, stream>>>(W2, w2t[0], w2t[1]);

    const int mt = Bc / 128;

    for (int ch = 0; ch < nch; ch++) {
        const int off = ch * Bc;
        const long long zoff = (long long)off * D_DIM;

        gemm_split<<<dim3(8 * mt * 4), 256, 0, stream>>>(
            zp[0] + zoff, zp[1] + zoff, 0LL,
            w1t[0], w1t[1], (long long)D_DIM * D_DIM,
            b1, D_DIM,
            nullptr, 0LL, 0, D_DIM,
            hp[0], hp[1], (long long)Bc * D_DIM,
            mt, 4, 1);

        gemm_split<<<dim3(8 * mt * 8), 256, 0, stream>>>(
            hp[0], hp[1], (long long)Bc * D_DIM,
            w2t[0], w2t[1], (long long)C_PAD * D_DIM,
            b2, C_DIM,
            Lb, (long long)Bc * C_DIM, C_DIM, C_DIM,
            nullptr, nullptr, 0LL,
            mt, 8, 0);

        gate_combine<<<dim3(Bc / 4), 256, 0, stream>>>(
            Lb, n_exp + off,
            out_logits + (size_t)off * C_DIM,
            out_gates + (size_t)off * K_EXP,
            Bc);
    }
}

// Round 7
// 479.232 us; speedup vs baseline: 3.2520x; 1.0779x over previous
//
#include <hip/hip_runtime.h>
#include <math.h>

#define B_SZ 8192
#define D_DIM 512
#define C_DIM 1000
#define C_PAD 1024
#define K_EXP 8
#define TEMP_INV 5.0f
#define EPS_N 1e-8f

typedef __attribute__((ext_vector_type(8))) short frag_ab;
typedef __attribute__((ext_vector_type(4))) float frag_cd;

__device__ __forceinline__ short f2bf(float f) {
    unsigned u = __builtin_bit_cast(unsigned, f);
    unsigned r = (u + 0x7fffu + ((u >> 16) & 1u)) >> 16;
    return (short)r;
}
__device__ __forceinline__ float bf2f(short s) {
    unsigned u = ((unsigned)(unsigned short)s) << 16;
    return __builtin_bit_cast(float, u);
}
// 2-plane split: v ~= s0 + s1, |residual| ~ 2^-18 |v|
__device__ __forceinline__ void split2(float v, short& s0, short& s1) {
    s0 = f2bf(v);
    s1 = f2bf(v - bf2f(s0));
}

// async global->LDS, 16B per lane (LDS dest wave-contiguous: base + lane*16)
__device__ __forceinline__ void gl_lds16(const short* g, short* l) {
    __builtin_amdgcn_global_load_lds(
        (const __attribute__((address_space(1))) unsigned int*)(const void*)g,
        (__attribute__((address_space(3))) unsigned int*)(void*)l,
        16, 0, 0);
}

// ---------------- one-time prep: transpose + 2-way bf16 split ----------------
__global__ __launch_bounds__(256) void prep_z(const float* __restrict__ z,
                                              short* __restrict__ p0, short* __restrict__ p1) {
    int idx = blockIdx.x * 256 + threadIdx.x;
    float v = z[idx];
    short a, b; split2(v, a, b);
    p0[idx] = a; p1[idx] = b;
}

// W1 [K][d][e] -> planes [K][e][d], LDS 32x32 tile transpose
__global__ __launch_bounds__(256) void prep_w1t(const float* __restrict__ W1,
                                                short* __restrict__ p0, short* __restrict__ p1) {
    __shared__ float t[32][33];
    const int k = blockIdx.z;
    const int d0 = blockIdx.x * 32;
    const int e0 = blockIdx.y * 32;
    const int tx = threadIdx.x & 31, ty = threadIdx.x >> 5;
    const float* src = W1 + ((size_t)k << 18);
#pragma unroll
    for (int r = 0; r < 4; r++) {
        int d = d0 + ty + 8 * r;
        t[ty + 8 * r][tx] = src[(size_t)d * 512 + e0 + tx];
    }
    __syncthreads();
#pragma unroll
    for (int r = 0; r < 4; r++) {
        int e = e0 + ty + 8 * r;
        int d = d0 + tx;
        float v = t[tx][ty + 8 * r];
        short a, b; split2(v, a, b);
        size_t o = ((size_t)k << 18) + (size_t)e * 512 + d;
        p0[o] = a; p1[o] = b;
    }
}

// W2 [K][e][c] -> planes [K][c_pad][e] (zero rows c>=1000), 32x32 tile transpose
__global__ __launch_bounds__(256) void prep_w2t(const float* __restrict__ W2,
                                                short* __restrict__ p0, short* __restrict__ p1) {
    __shared__ float t[32][33];
    const int k = blockIdx.z;
    const int e0 = blockIdx.x * 32;
    const int c0 = blockIdx.y * 32;
    const int tx = threadIdx.x & 31, ty = threadIdx.x >> 5;
    const float* src = W2 + (size_t)k * (D_DIM * C_DIM);
#pragma unroll
    for (int r = 0; r < 4; r++) {
        int e = e0 + ty + 8 * r;
        int c = c0 + tx;
        t[ty + 8 * r][tx] = (c < C_DIM) ? src[(size_t)e * C_DIM + c] : 0.f;
    }
    __syncthreads();
#pragma unroll
    for (int r = 0; r < 4; r++) {
        int c = c0 + ty + 8 * r;
        int e = e0 + tx;
        float v = t[tx][ty + 8 * r];
        short a, b; split2(v, a, b);
        size_t o = (size_t)k * (C_PAD * D_DIM) + (size_t)c * 512 + e;
        p0[o] = a; p1[o] = b;
    }
}

// ---------------- split-bf16 MFMA GEMM: 256x128 block, 128x64 wave tile ----------------
// Single-buffer 48 KB LDS, BK=32, 3 MFMA products (a0b0, a0b1, a1b0).
// Bank-swizzle: LDS slot c of row r holds global k-chunk c ^ ((r>>1)&3), so
// fragment reads spread each 16-lane issue group over all 8 bank-quads (2-way = free).
__global__ __launch_bounds__(256, 2) void gemm_split(
    const short* __restrict__ A0, const short* __restrict__ A1, long long aBatch,
    const short* __restrict__ B0, const short* __restrict__ B1, long long bBatch,
    const float* __restrict__ bias, int biasBatch,
    float* __restrict__ Cf, long long cBatch, int ldc, int Nout,
    short* __restrict__ H0, short* __restrict__ H1, long long hBatch,
    int mt, int nt, int mode)
{
    const int lin = blockIdx.x;
    const int k = lin & 7;                  // expert ↔ XCD affinity
    const int rem = lin >> 3;
    const int gm = (mt >= 2) ? 2 : 1;       // m-window (512-row L2 window)
    const int win = rem / (gm * nt);
    const int local = rem % (gm * nt);
    const int m0 = (win * gm + local / nt) * 256;
    const int n0 = (local % nt) * 128;

    const int tid = threadIdx.x;
    const int lane = tid & 63;
    const int wv = tid >> 6;
    const int wm = (wv & 1) * 128;          // wave tile: 128 rows x 64 cols
    const int wn = (wv >> 1) * 64;

    __shared__ short lds[24576];            // A: 2 planes x 8192, B: 2 planes x 4096

    const short* gA0 = A0 + (size_t)k * aBatch + (size_t)m0 * 512;
    const short* gA1 = A1 + (size_t)k * aBatch + (size_t)m0 * 512;
    const short* gB0 = B0 + (size_t)k * bBatch + (size_t)n0 * 512;
    const short* gB1 = B1 + (size_t)k * bBatch + (size_t)n0 * 512;
    short* ldsA = lds;
    short* ldsB = lds + 16384;

    frag_cd acc[8][4];
#pragma unroll
    for (int i = 0; i < 8; i++)
#pragma unroll
        for (int j = 0; j < 4; j++)
            acc[i][j] = (frag_cd){0.f, 0.f, 0.f, 0.f};

    const int srow = tid >> 2;              // 0..63
    const int sc   = tid & 3;               // LDS slot (dest chunk) — fixed by lane

    for (int k0 = 0; k0 < 512; k0 += 32) {
        const short* ga[2] = {gA0, gA1};
        const short* gb[2] = {gB0, gB1};
#pragma unroll
        for (int p = 0; p < 2; p++) {
#pragma unroll
            for (int hh = 0; hh < 4; hh++) {           // A: 256 rows
                int row = hh * 64 + srow;
                int gq = sc ^ ((row >> 1) & 3);        // source chunk (swizzled)
                gl_lds16(ga[p] + (size_t)row * 512 + k0 + gq * 8,
                         ldsA + p * 8192 + row * 32 + sc * 8);
            }
#pragma unroll
            for (int hh = 0; hh < 2; hh++) {           // B: 128 rows
                int row = hh * 64 + srow;
                int gq = sc ^ ((row >> 1) & 3);
                gl_lds16(gb[p] + (size_t)row * 512 + k0 + gq * 8,
                         ldsB + p * 4096 + row * 32 + sc * 8);
            }
        }
        __syncthreads();

        const int q = lane >> 4;                       // desired global k-chunk
        const int rb = lane & 15;

        frag_ab bfr[2][4];
#pragma unroll
        for (int p = 0; p < 2; p++)
#pragma unroll
            for (int j = 0; j < 4; j++) {
                int R = wn + j * 16 + rb;
                int slot = q ^ ((R >> 1) & 3);
                bfr[p][j] = *(const frag_ab*)(ldsB + p * 4096 + R * 32 + slot * 8);
            }

#pragma unroll
        for (int i = 0; i < 8; i++) {
            int R = wm + i * 16 + rb;
            int slot = q ^ ((R >> 1) & 3);
            frag_ab a0 = *(const frag_ab*)(ldsA + R * 32 + slot * 8);
            frag_ab a1 = *(const frag_ab*)(ldsA + 8192 + R * 32 + slot * 8);
#pragma unroll
            for (int j = 0; j < 4; j++) {
                frag_cd c = acc[i][j];
                c = __builtin_amdgcn_mfma_f32_16x16x32_bf16(a0, bfr[0][j], c, 0, 0, 0);
                c = __builtin_amdgcn_mfma_f32_16x16x32_bf16(a0, bfr[1][j], c, 0, 0, 0);
                c = __builtin_amdgcn_mfma_f32_16x16x32_bf16(a1, bfr[0][j], c, 0, 0, 0);
                acc[i][j] = c;
            }
        }
        __syncthreads();
    }

    // epilogue: C/D layout col=lane&15, row=(lane>>4)*4+reg
    const int r0 = (lane >> 4) * 4;
    const int cc = lane & 15;
    if (mode == 0) {
        float* C = Cf + (size_t)k * cBatch;
        const float* bb = bias + (size_t)k * biasBatch;
#pragma unroll
        for (int i = 0; i < 8; i++) {
            int rowb = m0 + wm + i * 16 + r0;
#pragma unroll
            for (int j = 0; j < 4; j++) {
                int col = n0 + wn + j * 16 + cc;
                if (col < Nout) {
                    float b = bb[col];
#pragma unroll
                    for (int r = 0; r < 4; r++)
                        C[(size_t)(rowb + r) * ldc + col] = acc[i][j][r] + b;
                }
            }
        }
    } else {
        short* h0 = H0 + (size_t)k * hBatch;
        short* h1 = H1 + (size_t)k * hBatch;
        const float* bb = bias + (size_t)k * biasBatch;
#pragma unroll
        for (int i = 0; i < 8; i++) {
            int rowb = m0 + wm + i * 16 + r0;
#pragma unroll
            for (int j = 0; j < 4; j++) {
                int col = n0 + wn + j * 16 + cc;
                float b = bb[col];
#pragma unroll
                for (int r = 0; r < 4; r++) {
                    float v = fmaxf(acc[i][j][r] + b, 0.f);
                    short s0, s1; split2(v, s0, s1);
                    size_t o = (size_t)(rowb + r) * 512 + col;
                    h0[o] = s0; h1[o] = s1;
                }
            }
        }
    }
}

// ---------------- gate + combine: one wave per sample, wave-synchronous ----------------
__global__ __launch_bounds__(256) void gate_combine(
    const float* __restrict__ L,
    const int* __restrict__ n_exp,
    float* __restrict__ out_logits,   // [Bc][C] (offset)
    float* __restrict__ out_gates,    // [Bc][K] (offset)
    int Bc)
{
    const int wv = threadIdx.x >> 6;
    const int lane = threadIdx.x & 63;
    const int b = blockIdx.x * 4 + wv;
    const size_t kcs = (size_t)Bc * C_DIM;
    const float* Lb = L + (size_t)b * C_DIM;

    __shared__ float Sm[4][64];
    __shared__ float Zm[4][8];

    float mx[K_EXP], Zs[K_EXP], dd[36];
#pragma unroll
    for (int k = 0; k < K_EXP; k++) { mx[k] = -INFINITY; Zs[k] = 0.f; }
#pragma unroll
    for (int p = 0; p < 36; p++) dd[p] = 0.f;

    for (int c = lane; c < C_DIM; c += 64) {
        float e[K_EXP];
#pragma unroll
        for (int k = 0; k < K_EXP; k++) {
            float l = Lb[(size_t)k * kcs + c];
            mx[k] = fmaxf(mx[k], l);
            e[k] = __expf(l);
            Zs[k] += e[k];
        }
        int idx = 0;
#pragma unroll
        for (int i = 0; i < K_EXP; i++)
#pragma unroll
            for (int j = i; j < K_EXP; j++) {
                dd[idx] = fmaf(e[i], e[j], dd[idx]);
                idx++;
            }
    }

#pragma unroll
    for (int off = 32; off > 0; off >>= 1) {
#pragma unroll
        for (int k = 0; k < K_EXP; k++) {
            mx[k] = fmaxf(mx[k], __shfl_xor(mx[k], off, 64));
            Zs[k] += __shfl_xor(Zs[k], off, 64);
        }
#pragma unroll
        for (int p = 0; p < 36; p++)
            dd[p] += __shfl_xor(dd[p], off, 64);
    }

    if (lane == 0) {
        int idx = 0;
#pragma unroll
        for (int i = 0; i < K_EXP; i++)
#pragma unroll
            for (int j = i; j < K_EXP; j++) {
                Sm[wv][i * 8 + j] = dd[idx];
                Sm[wv][j * 8 + i] = dd[idx];
                idx++;
            }
#pragma unroll
        for (int k = 0; k < K_EXP; k++) Zm[wv][k] = Zs[k];
    }

    const int ti = lane >> 3, tj = lane & 7;
    const float Zi = Zm[wv][ti], Zj = Zm[wv][tj];
    const float dij = Sm[wv][ti * 8 + tj];
    const float dii = Sm[wv][ti * 8 + ti];
    const float djj = Sm[wv][tj * 8 + tj];
    const float ni = sqrtf(dii) / Zi + EPS_N;
    const float nj = sqrtf(djj) / Zj + EPS_N;
    const float cosij = (dij / (Zi * Zj)) / (ni * nj);

    float conf[K_EXP];
#pragma unroll
    for (int k = 0; k < K_EXP; k++) conf[k] = __expf(mx[k]) / Zs[k];

    int i0 = 0; float bcf = conf[0];
#pragma unroll
    for (int k = 1; k < K_EXP; k++)
        if (conf[k] > bcf) { bcf = conf[k]; i0 = k; }
    unsigned sel = 1u << i0;
    const int n = n_exp[b];

    for (int t = 1; t < K_EXP; t++) {
        float v = ((sel >> tj) & 1u) ? cosij : -INFINITY;
        v = fmaxf(v, __shfl_xor(v, 1, 64));
        v = fmaxf(v, __shfl_xor(v, 2, 64));
        v = fmaxf(v, __shfl_xor(v, 4, 64));
        float dist = ((sel >> ti) & 1u) ? -INFINITY : 1.0f - v;
        float bv = dist; int bi = ti;
#pragma unroll
        for (int off = 8; off < 64; off <<= 1) {
            float ov = __shfl_xor(bv, off, 64);
            int oi = __shfl_xor(bi, off, 64);
            if (ov > bv || (ov == bv && oi < bi)) { bv = ov; bi = oi; }
        }
        if (t < n) sel |= 1u << bi;
    }

    float cmax = -INFINITY;
#pragma unroll
    for (int k = 0; k < K_EXP; k++)
        if ((sel >> k) & 1u) cmax = fmaxf(cmax, conf[k]);
    float g[K_EXP], gsum = 0.f;
#pragma unroll
    for (int k = 0; k < K_EXP; k++) {
        g[k] = ((sel >> k) & 1u) ? __expf((conf[k] - cmax) * TEMP_INV) : 0.f;
        gsum += g[k];
    }
    const float ginv = 1.0f / gsum;
#pragma unroll
    for (int k = 0; k < K_EXP; k++) g[k] *= ginv;

    if (lane == 0) {
        float4* og = (float4*)(out_gates + (size_t)b * K_EXP);
        og[0] = make_float4(g[0], g[1], g[2], g[3]);
        og[1] = make_float4(g[4], g[5], g[6], g[7]);
    }

    for (int c = lane; c < C_DIM; c += 64) {
        float o = 0.f;
#pragma unroll
        for (int k = 0; k < K_EXP; k++)
            o = fmaf(g[k], Lb[(size_t)k * kcs + c], o);
        out_logits[(size_t)b * C_DIM + c] = o;
    }
}

// ---------------- launch ----------------
extern "C" void kernel_launch(void* const* d_in, const int* in_sizes, int n_in,
                              void* d_out, int out_size, void* d_ws, size_t ws_size,
                              hipStream_t stream) {
    const float* z     = (const float*)d_in[0];
    const int*   n_exp = (const int*)d_in[1];
    const float* W1    = (const float*)d_in[2];
    const float* b1    = (const float*)d_in[3];
    const float* W2    = (const float*)d_in[4];
    const float* b2    = (const float*)d_in[5];
    float* out_logits = (float*)d_out;
    float* out_gates  = (float*)d_out + (size_t)B_SZ * C_DIM;

    const size_t zP   = (size_t)B_SZ * D_DIM * 2;
    const size_t w1P  = (size_t)K_EXP * D_DIM * D_DIM * 2;
    const size_t w2P  = (size_t)K_EXP * C_PAD * D_DIM * 2;
    const size_t fixedBytes = 2 * (zP + w1P + w2P);   // ~42 MB

    int nch = 1;
    while (nch < 32 && fixedBytes + (size_t)(B_SZ / nch) * 48384 > ws_size) nch *= 2;
    const int Bc = B_SZ / nch;

    char* w = (char*)d_ws;
    short* zp[2];  zp[0]  = (short*)w; zp[1]  = (short*)(w + zP);  w += 2 * zP;
    short* w1t[2]; w1t[0] = (short*)w; w1t[1] = (short*)(w + w1P); w += 2 * w1P;
    short* w2t[2]; w2t[0] = (short*)w; w2t[1] = (short*)(w + w2P); w += 2 * w2P;
    const size_t hP = (size_t)K_EXP * Bc * D_DIM * 2;
    short* hp[2];  hp[0]  = (short*)w; hp[1]  = (short*)(w + hP);  w += 2 * hP;
    float* Lb = (float*)w;

    prep_z <<<dim3((B_SZ * D_DIM) / 256), 256, 0, stream>>>(z, zp[0], zp[1]);
    prep_w1t<<<dim3(16, 16, K_EXP), 256, 0, stream>>>(W1, w1t[0], w1t[1]);
    prep_w2t<<<dim3(16, 32, K_EXP), 256, 0, stream>>>(W2, w2t[0], w2t[1]);

    const int mt = Bc / 256;    // 256-row m-tiles

    for (int ch = 0; ch < nch; ch++) {
        const int off = ch * Bc;
        const long long zoff = (long long)off * D_DIM;

        gemm_split<<<dim3(8 * mt * 4), 256, 0, stream>>>(
            zp[0] + zoff, zp[1] + zoff, 0LL,
            w1t[0], w1t[1], (long long)D_DIM * D_DIM,
            b1, D_DIM,
            nullptr, 0LL, 0, D_DIM,
            hp[0], hp[1], (long long)Bc * D_DIM,
            mt, 4, 1);

        gemm_split<<<dim3(8 * mt * 8), 256, 0, stream>>>(
            hp[0], hp[1], (long long)Bc * D_DIM,
            w2t[0], w2t[1], (long long)C_PAD * D_DIM,
            b2, C_DIM,
            Lb, (long long)Bc * C_DIM, C_DIM, C_DIM,
            nullptr, nullptr, 0LL,
            mt, 8, 0);

        gate_combine<<<dim3(Bc / 4), 256, 0, stream>>>(
            Lb, n_exp + off,
            out_logits + (size_t)off * C_DIM,
            out_gates + (size_t)off * K_EXP,
            Bc);
    }
}